// Round 23
// baseline (166.826 us; speedup 1.0000x reference)
//
#include <hip/hip_runtime.h>
#include <math.h>

// Problem constants
#define B_DIM 2
#define T_SEQ 1024
#define C_DIM 1024
#define H_DIM 16
#define N_DIM 64
#define M_ROWS (B_DIM * T_SEQ)   // 2048

// MFMA GEMM tiling (64x64 path, small GEMMs)
#define GBM 64
#define GBN 64
#define GBK 64
#define LDK 88
#define SW(r, c) ((c) ^ (((((r) >> 3) & 3)) << 3))
// 128x128 path: 16-short-granule swizzle on [128][40] tiles
#define SW16(r, c) ((c) ^ ((((r) >> 3) & 1) << 4))

typedef __attribute__((ext_vector_type(8))) short bf16x8;
typedef __attribute__((ext_vector_type(4))) float f32x4;
typedef unsigned short ushortx4 __attribute__((ext_vector_type(4)));
typedef unsigned short ushortx8 __attribute__((ext_vector_type(8)));

__device__ __forceinline__ unsigned short f2bf(float f) {
    unsigned int u = __float_as_uint(f);
    u = (u + 0x7FFFu + ((u >> 16) & 1u)) >> 16;   // RNE
    return (unsigned short)u;
}
__device__ __forceinline__ float bf2f(unsigned short h) {
    return __uint_as_float(((unsigned int)h) << 16);
}
__device__ __forceinline__ float fsigmoid(float x) {
    return 1.0f / (1.0f + __expf(-x));
}
__device__ __forceinline__ float ftanh(float x) {
    const float t = __expf(-2.0f * fabsf(x));
    const float r = (1.0f - t) / (1.0f + t);
    return copysignf(r, x);
}

__device__ __forceinline__ float wred64(float v) {
#pragma unroll
    for (int m = 32; m; m >>= 1) v += __shfl_xor(v, m);
    return v;
}

// ---------------- stage0: premix (1024 blocks) + all weight transposes (3712) -------
__global__ __launch_bounds__(256) void stage0_kernel(
    const float* __restrict__ x,
    const float* mr, const float* mk, const float* mv,
    const float* mw, const float* ma, const float* mg,
    unsigned short* xr, unsigned short* xk, unsigned short* xv,
    unsigned short* xw, unsigned short* xa, unsigned short* xg,
    const float* Wk, const float* Wv, const float* Wr,
    const float* w1p, const float* a1p, const float* v1p, const float* g1p,
    const float* a2p, const float* v2p, const float* g2p, const float* w2p,
    unsigned short* wtA, unsigned short* wtB, unsigned short* wtC,
    unsigned short* wt_w1, unsigned short* wt_a1, unsigned short* wt_v1,
    unsigned short* wt_g1, unsigned short* wt_a2, unsigned short* wt_v2,
    unsigned short* wt_g2, unsigned short* wt_w2)
{
    __shared__ float tile[32][33];
    const int bid0 = blockIdx.x;
    if (bid0 < 1024) {
        // -------- premix path --------
        const int g = bid0 * 256 + threadIdx.x;
        const size_t base = (size_t)g * 8;
        const int row = (int)(base >> 10);
        const int col = (int)(base & 1023);
        const int t_in = row & (T_SEQ - 1);

        const float* xp = x + (size_t)row * C_DIM + col;
        float4 a0 = *(const float4*)xp;
        float4 a1 = *(const float4*)(xp + 4);
        float4 p0 = make_float4(0.f, 0.f, 0.f, 0.f), p1 = p0;
        if (t_in > 0) {
            p0 = *(const float4*)(xp - C_DIM);
            p1 = *(const float4*)(xp - C_DIM + 4);
        }
        const float d0x = p0.x - a0.x, d0y = p0.y - a0.y, d0z = p0.z - a0.z, d0w = p0.w - a0.w;
        const float d1x = p1.x - a1.x, d1y = p1.y - a1.y, d1z = p1.z - a1.z, d1w = p1.w - a1.w;

        const float* ms[6] = {mr, mk, mv, mw, ma, mg};
        unsigned short* outs[6] = {xr, xk, xv, xw, xa, xg};
#pragma unroll
        for (int i = 0; i < 6; ++i) {
            const float4 m0 = *(const float4*)(ms[i] + col);
            const float4 m1 = *(const float4*)(ms[i] + col + 4);
            ushortx8 o;
            o[0] = f2bf(fmaf(d0x, m0.x, a0.x));
            o[1] = f2bf(fmaf(d0y, m0.y, a0.y));
            o[2] = f2bf(fmaf(d0z, m0.z, a0.z));
            o[3] = f2bf(fmaf(d0w, m0.w, a0.w));
            o[4] = f2bf(fmaf(d1x, m1.x, a1.x));
            o[5] = f2bf(fmaf(d1y, m1.y, a1.y));
            o[6] = f2bf(fmaf(d1z, m1.z, a1.z));
            o[7] = f2bf(fmaf(d1w, m1.w, a1.w));
            *(ushortx8*)(outs[i] + base) = o;
        }
        return;
    }
    // -------- transpose path --------
    const int bid = bid0 - 1024;
    const float* W; unsigned short* WT; int K, N, t0;
    if      (bid < 1024) { W = Wk;  WT = wtA;   K = 1024; N = 1024; t0 = 0;    }
    else if (bid < 2048) { W = Wv;  WT = wtB;   K = 1024; N = 1024; t0 = 1024; }
    else if (bid < 3072) { W = Wr;  WT = wtC;   K = 1024; N = 1024; t0 = 2048; }
    else if (bid < 3136) { W = w1p; WT = wt_w1; K = 1024; N = 64;   t0 = 3072; }
    else if (bid < 3200) { W = a1p; WT = wt_a1; K = 1024; N = 64;   t0 = 3136; }
    else if (bid < 3232) { W = v1p; WT = wt_v1; K = 1024; N = 32;   t0 = 3200; }
    else if (bid < 3392) { W = g1p; WT = wt_g1; K = 1024; N = 160;  t0 = 3232; }
    else if (bid < 3456) { W = a2p; WT = wt_a2; K = 64;   N = 1024; t0 = 3392; }
    else if (bid < 3488) { W = v2p; WT = wt_v2; K = 32;   N = 1024; t0 = 3456; }
    else if (bid < 3648) { W = g2p; WT = wt_g2; K = 160;  N = 1024; t0 = 3488; }
    else                 { W = w2p; WT = wt_w2; K = 64;   N = 1024; t0 = 3648; }
    const int lt = bid - t0;
    const int ntx = N >> 5;
    const int n0 = (lt % ntx) * 32;
    const int k0 = (lt / ntx) * 32;
    const int tx = threadIdx.x & 31, ty = threadIdx.x >> 5;
#pragma unroll
    for (int i = 0; i < 4; ++i)
        tile[ty + i * 8][tx] = W[(size_t)(k0 + ty + i * 8) * N + n0 + tx];
    __syncthreads();
#pragma unroll
    for (int i = 0; i < 4; ++i)
        WT[(size_t)(n0 + ty + i * 8) * K + k0 + tx] = f2bf(tile[tx][ty + i * 8]);
}

// ---------------- generic 64x64 MFMA GEMM core (register-prefetch pipelined) -------
__device__ __forceinline__ void gemm_core(
    unsigned short (*As)[LDK], unsigned short (*Bs)[LDK],
    const unsigned short* __restrict__ Aarr, int arow_stride,
    const unsigned short* __restrict__ WT, int K, int Nc, int bn0, int bm0,
    unsigned short* outp, unsigned short* outh, int hoff, int post)
{
    const int tid = threadIdx.x;
    const int lane = tid & 63;
    const int wid = tid >> 6;
    const int wr = wid >> 1, wc = wid & 1;
    const int l15 = lane & 15, l4 = lane >> 4;

    const int ar = tid >> 2;
    const int as = (tid & 3) << 4;
    const int row = bm0 + ar;
    const int brn = tid >> 2;
    const int bks = (tid & 3) << 4;
    const bool bn_ok = (bn0 + brn) < Nc;

    const int ra0 = wr * 32 + l15, ra1 = wr * 32 + 16 + l15;
    const int rb0 = wc * 32 + l15, rb1 = wc * 32 + 16 + l15;

    f32x4 acc[2][2] = {};
    const ushortx8 zz = {0, 0, 0, 0, 0, 0, 0, 0};
    ushortx8 pa0 = zz, pa1 = zz, pb0 = zz, pb1 = zz;

    if (as < K)      pa0 = *(const ushortx8*)(Aarr + (size_t)row * arow_stride + as);
    if (as + 8 < K)  pa1 = *(const ushortx8*)(Aarr + (size_t)row * arow_stride + as + 8);
    if (bn_ok && bks < K)     pb0 = *(const ushortx8*)(WT + (size_t)(bn0 + brn) * K + bks);
    if (bn_ok && bks + 8 < K) pb1 = *(const ushortx8*)(WT + (size_t)(bn0 + brn) * K + bks + 8);

    for (int k0 = 0; k0 < K; k0 += GBK) {
        *(ushortx8*)&As[ar][SW(ar, as)] = pa0;
        *(ushortx8*)&As[ar][SW(ar, as + 8)] = pa1;
        *(ushortx8*)&Bs[brn][SW(brn, bks)] = pb0;
        *(ushortx8*)&Bs[brn][SW(brn, bks + 8)] = pb1;
        __syncthreads();

        const int kn = k0 + GBK;
        if (kn < K) {
            pa0 = zz; pa1 = zz; pb0 = zz; pb1 = zz;
            if (kn + as < K)
                pa0 = *(const ushortx8*)(Aarr + (size_t)row * arow_stride + kn + as);
            if (kn + as + 8 < K)
                pa1 = *(const ushortx8*)(Aarr + (size_t)row * arow_stride + kn + as + 8);
            if (bn_ok && kn + bks < K)
                pb0 = *(const ushortx8*)(WT + (size_t)(bn0 + brn) * K + kn + bks);
            if (bn_ok && kn + bks + 8 < K)
                pb1 = *(const ushortx8*)(WT + (size_t)(bn0 + brn) * K + kn + bks + 8);
        }

#pragma unroll
        for (int ks = 0; ks < 2; ++ks) {
            const int cc = ks * 32 + l4 * 8;
            bf16x8 af0 = *(const bf16x8*)&As[ra0][SW(ra0, cc)];
            bf16x8 af1 = *(const bf16x8*)&As[ra1][SW(ra1, cc)];
            bf16x8 bg0 = *(const bf16x8*)&Bs[rb0][SW(rb0, cc)];
            bf16x8 bg1 = *(const bf16x8*)&Bs[rb1][SW(rb1, cc)];
            acc[0][0] = __builtin_amdgcn_mfma_f32_16x16x32_bf16(af0, bg0, acc[0][0], 0, 0, 0);
            acc[0][1] = __builtin_amdgcn_mfma_f32_16x16x32_bf16(af0, bg1, acc[0][1], 0, 0, 0);
            acc[1][0] = __builtin_amdgcn_mfma_f32_16x16x32_bf16(af1, bg0, acc[1][0], 0, 0, 0);
            acc[1][1] = __builtin_amdgcn_mfma_f32_16x16x32_bf16(af1, bg1, acc[1][1], 0, 0, 0);
        }
        __syncthreads();
    }

#pragma unroll
    for (int fi = 0; fi < 2; ++fi)
#pragma unroll
        for (int fj = 0; fj < 2; ++fj) {
            const int ocol = bn0 + wc * 32 + fj * 16 + l15;
            if (ocol < Nc) {
#pragma unroll
                for (int p = 0; p < 4; ++p) {
                    const int orow = bm0 + wr * 32 + fi * 16 + l4 * 4 + p;
                    float v = acc[fi][fj][p];
                    if (post == 1) v = ftanh(v);
                    else if (post == 2) v = fsigmoid(v);
                    if (outh)
                        outh[(size_t)orow * 320 + hoff + ocol] = f2bf(v);
                    else
                        outp[(size_t)orow * 1024 + ocol] = f2bf(v);
                }
            }
        }
}

// ---------------- 128x128 MFMA GEMM core (K=1024, register-prefetch pipelined) ------
__device__ __forceinline__ void gemm128_core(
    const unsigned short* __restrict__ A,
    const unsigned short* __restrict__ WT,
    int bm0, int bn0,
    unsigned short (*As)[40], unsigned short (*Bs)[40],
    f32x4 (*acc)[4])
{
    const int tid = threadIdx.x;
    const int lane = tid & 63;
    const int w = tid >> 6;
    const int wr = w >> 1, wc = w & 1;
    const int l15 = lane & 15, l4 = lane >> 4;
    const int sr = tid >> 1;
    const int sc = (tid & 1) << 4;
    const int ssc = SW16(sr, sc);

    const unsigned short* ap = A + (size_t)(bm0 + sr) * 1024 + sc;
    const unsigned short* bp = WT + (size_t)(bn0 + sr) * 1024 + sc;

    ushortx8 av0 = *(const ushortx8*)(ap);
    ushortx8 av1 = *(const ushortx8*)(ap + 8);
    ushortx8 bv0 = *(const ushortx8*)(bp);
    ushortx8 bv1 = *(const ushortx8*)(bp + 8);

    for (int k0 = 0; k0 < 1024; k0 += 32) {
        *(ushortx8*)&As[sr][ssc] = av0;
        *(ushortx8*)&As[sr][ssc + 8] = av1;
        *(ushortx8*)&Bs[sr][ssc] = bv0;
        *(ushortx8*)&Bs[sr][ssc + 8] = bv1;
        __syncthreads();

        const int kn = (k0 + 32 < 1024) ? k0 + 32 : k0;   // redundant tail reload
        av0 = *(const ushortx8*)(ap + kn);
        av1 = *(const ushortx8*)(ap + kn + 8);
        bv0 = *(const ushortx8*)(bp + kn);
        bv1 = *(const ushortx8*)(bp + kn + 8);

        bf16x8 af[4], bg[4];
#pragma unroll
        for (int f = 0; f < 4; ++f) {
            const int ra = wr * 64 + f * 16 + l15;
            const int rb = wc * 64 + f * 16 + l15;
            af[f] = *(const bf16x8*)&As[ra][SW16(ra, l4 * 8)];
            bg[f] = *(const bf16x8*)&Bs[rb][SW16(rb, l4 * 8)];
        }
#pragma unroll
        for (int fi = 0; fi < 4; ++fi)
#pragma unroll
            for (int fj = 0; fj < 4; ++fj)
                acc[fi][fj] = __builtin_amdgcn_mfma_f32_16x16x32_bf16(
                    af[fi], bg[fj], acc[fi][fj], 0, 0, 0);
        __syncthreads();
    }
}

// ---------------- stage-1 FUSED: 384 big-path + 192 small-path blocks ----------------
__global__ __launch_bounds__(256) void gemm_s1_kernel(
    const unsigned short* xr, const unsigned short* xk, const unsigned short* xv,
    const unsigned short* xw, const unsigned short* xa, const unsigned short* xg,
    const unsigned short* wtA, const unsigned short* wtB, const unsigned short* wtC,
    const unsigned short* wt_a1, const unsigned short* wt_v1,
    const unsigned short* wt_g1, const unsigned short* wt_w1,
    unsigned short* b_r, unsigned short* b_k, unsigned short* b_v,
    unsigned short* h_cat)
{
    __shared__ __align__(16) char sarena[22528];
    const int bid = blockIdx.x;
    if (bid < 384) {
        unsigned short (*As)[40] = (unsigned short (*)[40])sarena;
        unsigned short (*Bs)[40] = (unsigned short (*)[40])(sarena + 10240);
        const int g = bid >> 7;
        const int sub = bid & 127;
        const int bn0 = (sub & 7) * 128;
        const int bm0 = (sub >> 3) * 128;
        const unsigned short* A = (g == 0) ? xr : (g == 1) ? xk : xv;
        const unsigned short* WT = (g == 0) ? wtC : (g == 1) ? wtA : wtB;
        unsigned short* O = (g == 0) ? b_r : (g == 1) ? b_k : b_v;

        f32x4 acc[4][4] = {};
        gemm128_core(A, WT, bm0, bn0, As, Bs, acc);

        const int lane = threadIdx.x & 63;
        const int w = threadIdx.x >> 6;
        const int wr = w >> 1, wc = w & 1;
        const int l15 = lane & 15, l4 = lane >> 4;
#pragma unroll
        for (int fi = 0; fi < 4; ++fi)
#pragma unroll
            for (int fj = 0; fj < 4; ++fj) {
                const int ocol = bn0 + wc * 64 + fj * 16 + l15;
#pragma unroll
                for (int p = 0; p < 4; ++p) {
                    const int orow = bm0 + wr * 64 + fi * 16 + l4 * 4 + p;
                    O[(size_t)orow * 1024 + ocol] = f2bf(acc[fi][fj][p]);
                }
            }
    } else {
        unsigned short (*As)[LDK] = (unsigned short (*)[LDK])sarena;
        unsigned short (*Bs)[LDK] = (unsigned short (*)[LDK])(sarena + 11264);
        const int sid = bid - 384;
        const int nt = sid % 6;
        const int bm0 = (sid / 6) * 64;
        const unsigned short* A; const unsigned short* WT;
        int Nc, nb = 0, hoff, post = 0;
        if (nt == 0)      { A = xa; WT = wt_a1; hoff = 0;   Nc = 64; }
        else if (nt == 1) { A = xv; WT = wt_v1; hoff = 64;  Nc = 32; }
        else if (nt < 5)  { A = xg; WT = wt_g1; hoff = 96;  Nc = 160; nb = nt - 2; post = 2; }
        else              { A = xw; WT = wt_w1; hoff = 256; Nc = 64; post = 1; }
        gemm_core(As, Bs, A, 1024, WT, 1024, Nc, nb * 64, bm0,
                  nullptr, h_cat, hoff, post);
    }
}

// ---------------- stage-2: 4 GEMMs in one launch (A = h_cat, dense planar outs) -----
__global__ __launch_bounds__(256) void gemm_s2_kernel(
    const unsigned short* __restrict__ h_cat,
    const unsigned short* wt_a2, const unsigned short* wt_v2,
    const unsigned short* wt_g2, const unsigned short* wt_w2,
    unsigned short* b_a, unsigned short* b_vg, unsigned short* b_g,
    unsigned short* b_wl)
{
    __shared__ unsigned short As[GBM][LDK];
    __shared__ unsigned short Bs[GBN][LDK];
    const int g = blockIdx.x >> 4;
    const int nb = blockIdx.x & 15;
    const int bm0 = blockIdx.y * GBM;
    const unsigned short* WT;
    unsigned short* outp; int K, aoff;
    if      (g == 0) { WT = wt_a2; K = 64;  aoff = 0;   outp = b_a; }
    else if (g == 1) { WT = wt_v2; K = 32;  aoff = 64;  outp = b_vg; }
    else if (g == 2) { WT = wt_g2; K = 160; aoff = 96;  outp = b_g; }
    else             { WT = wt_w2; K = 64;  aoff = 256; outp = b_wl; }
    gemm_core(As, Bs, h_cat + aoff, 320, WT, K, 1024, nb * 64, bm0,
              outp, nullptr, 0, 0);
}

// ---------------- final GEMM (128x128): out = y_bf @ W_o + residual (f32 out) -------
__global__ __launch_bounds__(256) void gemm_final128_kernel(
    const unsigned short* __restrict__ Y, const unsigned short* __restrict__ WT,
    const float* __restrict__ addend, float* __restrict__ out)
{
    __shared__ unsigned short As[128][40];
    __shared__ unsigned short Bs[128][40];
    const int bn0 = blockIdx.x * 128;
    const int bm0 = blockIdx.y * 128;

    f32x4 acc[4][4] = {};
    gemm128_core(Y, WT, bm0, bn0, As, Bs, acc);

    const int lane = threadIdx.x & 63;
    const int w = threadIdx.x >> 6;
    const int wr = w >> 1, wc = w & 1;
    const int l15 = lane & 15, l4 = lane >> 4;
#pragma unroll
    for (int fi = 0; fi < 4; ++fi)
#pragma unroll
        for (int fj = 0; fj < 4; ++fj) {
            const int ocol = bn0 + wc * 64 + fj * 16 + l15;
#pragma unroll
            for (int p = 0; p < 4; ++p) {
                const int orow = bm0 + wr * 64 + fi * 16 + l4 * 4 + p;
                out[(size_t)orow * 1024 + ocol] =
                    acc[fi][fj][p] + addend[(size_t)orow * 1024 + ocol];
            }
        }
}

// ---------------- chunked-scan PREP (6-barrier version: E folded into D stores,
//                  F2 folded into F via direct bf16 writes) ------------------------
// LDS layout (53,120 B; 3 blocks/CU):
//  0      tB[32][72]      4608
//  4608   tK[32][72]      4608
//  9216   tR[32][72]      4608
//  13824  tBT[64][40]     5120
//  18944  VlT[64][40]     5120
//  24064  egT[32][40]     2560
//  26624  W32s[32][66]f32 8448 (dead after C) | cg[32][33] @26624 (D..F)
//  30848  dg[32][33] @30848 (D..F) | fT[32][40] @30848 (G-a..)
//  35072  fg[32][33]      4224
//  39296  tA[32][72]      4608 (reads end in F) | ZB[64][40] @39296 (written in F)
//  44416  EWZ f32 8192 (A..B only) | KtT[64][40] @44416 (G-a..)
//  49536  DhB[32][40]     2560 (written in F, read G-a; over dead EWZ tail)
//  52864  w31s            256
__global__ __launch_bounds__(256) void chunk_prep_kernel(
    const unsigned short* __restrict__ b_wl, const unsigned short* __restrict__ b_k,
    const unsigned short* __restrict__ b_a, const unsigned short* __restrict__ b_vg,
    const unsigned short* __restrict__ b_r,
    unsigned short* __restrict__ b_v,
    const float* __restrict__ v_first,
    const float* w0, const float* a0, const float* v0,
    const float* k_k, const float* k_a, const float* r_k,
    float* __restrict__ TB,
    unsigned short* __restrict__ Gt, unsigned short* __restrict__ LRt,
    unsigned short* __restrict__ VcT, float* __restrict__ Wl,
    unsigned short* __restrict__ Oi)
{
    __shared__ __align__(16) char smem[53120];
    unsigned short (*tB)[72]  = (unsigned short (*)[72])(smem + 0);
    unsigned short (*tK)[72]  = (unsigned short (*)[72])(smem + 4608);
    unsigned short (*tR)[72]  = (unsigned short (*)[72])(smem + 9216);
    unsigned short (*tBT)[40] = (unsigned short (*)[40])(smem + 13824);
    unsigned short (*VlT)[40] = (unsigned short (*)[40])(smem + 18944);
    unsigned short (*egT)[40] = (unsigned short (*)[40])(smem + 24064);
    float (*W32s)[66]         = (float (*)[66])(smem + 26624);
    float (*cg)[33]           = (float (*)[33])(smem + 26624);
    float (*dg)[33]           = (float (*)[33])(smem + 30848);
    unsigned short (*fT)[40]  = (unsigned short (*)[40])(smem + 30848);
    float (*fg)[33]           = (float (*)[33])(smem + 35072);
    unsigned short (*tA)[72]  = (unsigned short (*)[72])(smem + 39296);
    unsigned short (*ZB)[40]  = (unsigned short (*)[40])(smem + 39296);
    float* EWZ                = (float*)(smem + 44416);
    unsigned short (*KtT)[40] = (unsigned short (*)[40])(smem + 44416);
    unsigned short (*DhB)[40] = (unsigned short (*)[40])(smem + 49536);
    float* w31s               = (float*)(smem + 52864);

    const int tid = threadIdx.x;
    const int lane = tid & 63;
    const int w = tid >> 6;
    const int l15 = lane & 15, l4 = lane >> 4;
    const int bhc = blockIdx.x;
    const int bh = bhc >> 5, ck = bhc & 31;
    const int b = bh >> 4, h = bh & 15;
    const int cglob = h * 64 + lane;

    // ---- Phase A: planar loads + stage3 elementwise (fast-exp) ----
    const float kkc = k_k[cglob], kac = k_a[cglob];
    const float a0c = a0[cglob], v0c = v0[cglob];
    const float w0c = w0[cglob], rkc = r_k[cglob];
#pragma unroll
    for (int q = 0; q < 8; ++q) {
        const int tq = w * 8 + q;
        const int row = b * 1024 + ck * 32 + tq;
        const size_t gi = (size_t)row * 1024 + cglob;
        const float kl = bf2f(b_k[gi]);
        const float kkv = kl * kkc;
        const float ss = wred64(kkv * kkv);
        const float kkn = kkv / fmaxf(sqrtf(ss), 1e-12f);
        const float a = fsigmoid(a0c + bf2f(b_a[gi]));
        const float u = w0c + bf2f(b_wl[gi]);
        const float lnw = -__logf(1.0f + __expf(-u)) - 0.5f;
        const float ew = __expf(-__expf(lnw));
        const float sv = fsigmoid(v0c + bf2f(b_vg[gi]));
        const float vl = bf2f(b_v[gi]);
        const float v = fmaf(v_first[gi] - vl, sv, vl);
        const float ko = kl * (1.0f + (a - 1.0f) * kac);
        const unsigned short rbf = b_r[gi];
        const float r1f = bf2f(rbf);
        const unsigned short vbf = f2bf(v);
        b_v[gi] = vbf;

        const float t3 = wred64(r1f * ko * rkc);
        if (lane == 0) TB[bh * 1024 + ck * 32 + tq] = t3;

        EWZ[tq * 64 + lane] = ew;
        tA[tq][lane] = f2bf(-kkn);
        tB[tq][lane] = f2bf(kkn * a);
        tK[tq][lane] = f2bf(ko);
        tR[tq][lane] = rbf;
        VlT[lane][tq] = vbf;
    }
    __syncthreads();

    // ---- Phase B: decay cumprods (wave 0); EWZ dead afterwards ----
    if (w == 0) {
        float run = 1.0f;
        for (int t = 0; t < 32; ++t) {
            run *= EWZ[t * 64 + lane];
            W32s[t][lane] = run;
        }
    }
    __syncthreads();

    // ---- Phase C: tildes in place + tBT; save W31 before D overwrites ----
#pragma unroll
    for (int q = 0; q < 8; ++q) {
        const int tq = w * 8 + q;
        const float Wt = W32s[tq][lane];
        const float Wm1 = tq ? W32s[tq - 1][lane] : 1.0f;
        const float iw = 1.0f / Wt;
        tA[tq][lane] = f2bf(bf2f(tA[tq][lane]) * Wm1);
        const unsigned short tb = f2bf(bf2f(tB[tq][lane]) * iw);
        tB[tq][lane] = tb;
        tBT[lane][tq] = tb;
        tK[tq][lane] = f2bf(bf2f(tK[tq][lane]) * iw);
        tR[tq][lane] = f2bf(bf2f(tR[tq][lane]) * Wt);
    }
    if (tid < 64) w31s[tid] = W32s[31][tid];
    __syncthreads();

    // ---- Phase D: four 32x32 Grams via MFMA; triangle masks applied at store ----
    {
        const unsigned short (*Am)[72] = (w == 0 || w == 2) ? tB : tK;
        const unsigned short (*Bm)[72] = (w < 2) ? tA : tR;
        f32x4 gacc[2][2] = {};
#pragma unroll
        for (int kh = 0; kh < 2; ++kh) {
            const int cc = kh * 32 + l4 * 8;
            bf16x8 ax0 = *(const bf16x8*)&Am[l15][cc];
            bf16x8 ax1 = *(const bf16x8*)&Am[16 + l15][cc];
            bf16x8 bx0 = *(const bf16x8*)&Bm[l15][cc];
            bf16x8 bx1 = *(const bf16x8*)&Bm[16 + l15][cc];
            gacc[0][0] = __builtin_amdgcn_mfma_f32_16x16x32_bf16(ax0, bx0, gacc[0][0], 0, 0, 0);
            gacc[0][1] = __builtin_amdgcn_mfma_f32_16x16x32_bf16(ax0, bx1, gacc[0][1], 0, 0, 0);
            gacc[1][0] = __builtin_amdgcn_mfma_f32_16x16x32_bf16(ax1, bx0, gacc[1][0], 0, 0, 0);
            gacc[1][1] = __builtin_amdgcn_mfma_f32_16x16x32_bf16(ax1, bx1, gacc[1][1], 0, 0, 0);
        }
#pragma unroll
        for (int mt = 0; mt < 2; ++mt)
#pragma unroll
            for (int nt = 0; nt < 2; ++nt) {
                const int col = nt * 16 + l15;
                if (w == 2) {
                    // egT[col][rw] kept when rw <= col (else 0)
                    ushortx4 st;
#pragma unroll
                    for (int p = 0; p < 4; ++p) {
                        const int rw = mt * 16 + l4 * 4 + p;
                        st[p] = (rw <= col) ? f2bf(gacc[mt][nt][p]) : (unsigned short)0;
                    }
                    *(ushortx4*)&egT[col][mt * 16 + l4 * 4] = st;
                } else {
#pragma unroll
                    for (int p = 0; p < 4; ++p) {
                        const int rw = mt * 16 + l4 * 4 + p;
                        if (w == 0)      cg[rw][col] = (rw < col)  ? gacc[mt][nt][p] : 0.0f;
                        else if (w == 1) dg[rw][col] = (col > rw)  ? gacc[mt][nt][p] : 0.0f;
                        else             fg[rw][col] = (rw <= col) ? gacc[mt][nt][p] : 0.0f;
                    }
                }
            }
    }
    __syncthreads();

    // ---- Phase F: triangular recurrences, register-resident prefix;
    //      direct bf16 writes (ZB over tA after reads; DhB over dead EWZ tail) ----
    if (w == 0) {
        float z[32];
#pragma unroll
        for (int i = 0; i < 32; ++i) {
            float v0_ = bf2f(tA[i][lane]), v1_ = 0.0f, v2_ = 0.0f, v3_ = 0.0f;
#pragma unroll
            for (int j = 0; j < 32; ++j) {
                if (j < i) {
                    const float c_ = cg[j][i];
                    if ((j & 3) == 0)      v0_ = fmaf(c_, z[j], v0_);
                    else if ((j & 3) == 1) v1_ = fmaf(c_, z[j], v1_);
                    else if ((j & 3) == 2) v2_ = fmaf(c_, z[j], v2_);
                    else                   v3_ = fmaf(c_, z[j], v3_);
                }
            }
            z[i] = (v0_ + v1_) + (v2_ + v3_);
        }
#pragma unroll
        for (int i = 0; i < 32; ++i)
            ZB[lane][i] = f2bf(z[i]);
    } else if (w == 1 && lane < 32) {
        float dh[32];
#pragma unroll
        for (int t = 0; t < 32; ++t) {
            float v0_ = dg[lane][t], v1_ = 0.0f, v2_ = 0.0f, v3_ = 0.0f;
#pragma unroll
            for (int j = 0; j < 32; ++j) {
                if (j < t) {
                    const float c_ = cg[j][t];
                    if ((j & 3) == 0)      v0_ = fmaf(c_, dh[j], v0_);
                    else if ((j & 3) == 1) v1_ = fmaf(c_, dh[j], v1_);
                    else if ((j & 3) == 2) v2_ = fmaf(c_, dh[j], v2_);
                    else                   v3_ = fmaf(c_, dh[j], v3_);
                }
            }
            dh[t] = (v0_ + v1_) + (v2_ + v3_);
        }
#pragma unroll
        for (int t = 0; t < 32; ++t)
            DhB[lane][t] = f2bf(dh[t]);
    }
    __syncthreads();

    const size_t cb2048 = (size_t)bhc * 2048;
    const size_t cb4096 = (size_t)bhc * 4096;

    // ---- Phase G-a ----
    if (w == 0) {
#pragma unroll
        for (int mt = 0; mt < 2; ++mt)
#pragma unroll
            for (int nt = 0; nt < 2; ++nt) {
                f32x4 cacc;
#pragma unroll
                for (int p = 0; p < 4; ++p) cacc[p] = fg[mt * 16 + l4 * 4 + p][nt * 16 + l15];
                bf16x8 ax = *(const bf16x8*)&DhB[mt * 16 + l15][l4 * 8];
                bf16x8 bx = *(const bf16x8*)&egT[nt * 16 + l15][l4 * 8];
                cacc = __builtin_amdgcn_mfma_f32_16x16x32_bf16(ax, bx, cacc, 0, 0, 0);
                ushortx4 st;
#pragma unroll
                for (int p = 0; p < 4; ++p) st[p] = f2bf(cacc[p]);
                *(ushortx4*)&fT[nt * 16 + l15][mt * 16 + l4 * 4] = st;
            }
    } else if (w == 1) {
#pragma unroll
        for (int mt = 0; mt < 2; ++mt)
#pragma unroll
            for (int nt = 0; nt < 4; ++nt) {
                bf16x8 ax = *(const bf16x8*)&DhB[mt * 16 + l15][l4 * 8];
                bf16x8 bx = *(const bf16x8*)&tBT[nt * 16 + l15][l4 * 8];
                f32x4 cacc = {};
                cacc = __builtin_amdgcn_mfma_f32_16x16x32_bf16(ax, bx, cacc, 0, 0, 0);
                const int col = nt * 16 + l15;
                const float w31c = w31s[col];
                ushortx4 st;
#pragma unroll
                for (int p = 0; p < 4; ++p) {
                    const int rw = mt * 16 + l4 * 4 + p;
                    st[p] = f2bf((cacc[p] + bf2f(tK[rw][col])) * w31c);
                }
                *(ushortx4*)&KtT[col][mt * 16 + l4 * 4] = st;
            }
    } else if (w == 2) {
#pragma unroll
        for (int mt = 0; mt < 4; ++mt)
#pragma unroll
            for (int nt = 0; nt < 4; ++nt) {
                bf16x8 ax = *(const bf16x8*)&tBT[mt * 16 + l15][l4 * 8];
                bf16x8 bx = *(const bf16x8*)&ZB[nt * 16 + l15][l4 * 8];
                f32x4 cacc = {};
                cacc = __builtin_amdgcn_mfma_f32_16x16x32_bf16(ax, bx, cacc, 0, 0, 0);
                const int kcol = nt * 16 + l15;
#pragma unroll
                for (int p = 0; p < 4; ++p) {
                    const int n_ = mt * 16 + l4 * 4 + p;
                    LRt[cb4096 + n_ * 64 + kcol] = f2bf(cacc[p] * w31s[n_]);
                }
            }
    } else {
#pragma unroll
        for (int mt = 0; mt < 2; ++mt)
#pragma unroll
            for (int nt = 0; nt < 4; ++nt) {
                bf16x8 ax = *(const bf16x8*)&egT[mt * 16 + l15][l4 * 8];
                bf16x8 bx = *(const bf16x8*)&ZB[nt * 16 + l15][l4 * 8];
                f32x4 cacc = {};
                cacc = __builtin_amdgcn_mfma_f32_16x16x32_bf16(ax, bx, cacc, 0, 0, 0);
                const int ncol = nt * 16 + l15;
#pragma unroll
                for (int p = 0; p < 4; ++p) {
                    const int t_ = mt * 16 + l4 * 4 + p;
                    Gt[cb2048 + t_ * 64 + ncol] = f2bf(cacc[p] + bf2f(tR[t_][ncol]));
                }
            }
    }
    __syncthreads();

    // ---- Phase G-b ----
    if (w < 2) {
#pragma unroll
        for (int mt = 0; mt < 2; ++mt)
#pragma unroll
            for (int ntl = 0; ntl < 2; ++ntl) {
                const int nt = w * 2 + ntl;
                bf16x8 ax = *(const bf16x8*)&fT[mt * 16 + l15][l4 * 8];
                bf16x8 bx = *(const bf16x8*)&VlT[nt * 16 + l15][l4 * 8];
                f32x4 cacc = {};
                cacc = __builtin_amdgcn_mfma_f32_16x16x32_bf16(ax, bx, cacc, 0, 0, 0);
                const int vcol = nt * 16 + l15;
#pragma unroll
                for (int p = 0; p < 4; ++p) {
                    const int t_ = mt * 16 + l4 * 4 + p;
                    Oi[cb2048 + t_ * 64 + vcol] = f2bf(cacc[p]);
                }
            }
    } else {
#pragma unroll
        for (int mtl = 0; mtl < 2; ++mtl)
#pragma unroll
            for (int nt = 0; nt < 4; ++nt) {
                const int mt = (w - 2) * 2 + mtl;
                bf16x8 ax = *(const bf16x8*)&VlT[mt * 16 + l15][l4 * 8];
                bf16x8 bx = *(const bf16x8*)&KtT[nt * 16 + l15][l4 * 8];
                f32x4 cacc = {};
                cacc = __builtin_amdgcn_mfma_f32_16x16x32_bf16(ax, bx, cacc, 0, 0, 0);
                const int ncol = nt * 16 + l15;
                ushortx4 st;
#pragma unroll
                for (int p = 0; p < 4; ++p) st[p] = f2bf(cacc[p]);
                *(ushortx4*)&VcT[cb4096 + (size_t)ncol * 64 + mt * 16 + l4 * 4] = st;
            }
    }
    if (tid < 64) Wl[(size_t)bhc * 64 + tid] = w31s[tid];
}

// ---------------- chunked-scan SEQ (128 blocks) + W_o transpose (1024 blocks) -------
struct SeqRegs {
    bf16x8 g[4];
    bf16x8 lr[8];
    ushortx4 vc[4];
    float wl[4];
    ushortx4 oi[2];
};

__device__ __forceinline__ void load_chunk(
    SeqRegs& R,
    const unsigned short* __restrict__ gt, const unsigned short* __restrict__ lr,
    const unsigned short* __restrict__ vct, const float* __restrict__ wlp,
    const unsigned short* __restrict__ oi, int l15, int l4, int vg)
{
#pragma unroll
    for (int tt = 0; tt < 2; ++tt) {
        R.g[tt * 2 + 0] = *(const bf16x8*)&gt[(tt * 16 + l15) * 64 + l4 * 8];
        R.g[tt * 2 + 1] = *(const bf16x8*)&gt[(tt * 16 + l15) * 64 + 32 + l4 * 8];
        R.oi[tt] = *(const ushortx4*)&oi[(tt * 16 + l15) * 64 + vg * 16 + l4 * 4];
    }
#pragma unroll
    for (int nt = 0; nt < 4; ++nt) {
        R.lr[nt * 2 + 0] = *(const bf16x8*)&lr[(nt * 16 + l15) * 64 + l4 * 8];
        R.lr[nt * 2 + 1] = *(const bf16x8*)&lr[(nt * 16 + l15) * 64 + 32 + l4 * 8];
        R.vc[nt] = *(const ushortx4*)&vct[(nt * 16 + l15) * 64 + vg * 16 + l4 * 4];
        R.wl[nt] = wlp[nt * 16 + l15];
    }
}

__device__ __forceinline__ void seq_step(
    f32x4* sC, const SeqRegs& R, unsigned short (*Sst)[80],
    unsigned short* __restrict__ o, int b, int h, int c, int vg, int l15, int l4)
{
#pragma unroll
    for (int nt = 0; nt < 4; ++nt)
#pragma unroll
        for (int p = 0; p < 4; ++p)
            Sst[l4 * 4 + p][nt * 16 + l15] = f2bf(sC[nt][p]);
    __builtin_amdgcn_wave_barrier();
    bf16x8 a0 = *(const bf16x8*)&Sst[l15][l4 * 8];
    bf16x8 a1 = *(const bf16x8*)&Sst[l15][32 + l4 * 8];
    __builtin_amdgcn_wave_barrier();

    f32x4 oacc[2] = {};
#pragma unroll
    for (int tt = 0; tt < 2; ++tt) {
        oacc[tt] = __builtin_amdgcn_mfma_f32_16x16x32_bf16(a0, R.g[tt * 2 + 0], oacc[tt], 0, 0, 0);
        oacc[tt] = __builtin_amdgcn_mfma_f32_16x16x32_bf16(a1, R.g[tt * 2 + 1], oacc[tt], 0, 0, 0);
    }
    f32x4 lac[4] = {};
#pragma unroll
    for (int nt = 0; nt < 4; ++nt) {
        lac[nt] = __builtin_amdgcn_mfma_f32_16x16x32_bf16(a0, R.lr[nt * 2 + 0], lac[nt], 0, 0, 0);
        lac[nt] = __builtin_amdgcn_mfma_f32_16x16x32_bf16(a1, R.lr[nt * 2 + 1], lac[nt], 0, 0, 0);
    }

#pragma unroll
    for (int nt = 0; nt < 4; ++nt) {
        const float wlv = R.wl[nt];
#pragma unroll
        for (int p = 0; p < 4; ++p)
            sC[nt][p] = fmaf(sC[nt][p], wlv, lac[nt][p] + bf2f(R.vc[nt][p]));
    }

#pragma unroll
    for (int tt = 0; tt < 2; ++tt) {
        const int trow = b * 1024 + c * 32 + tt * 16 + l15;
        ushortx4 ov;
        ov.x = f2bf(oacc[tt][0] + bf2f(R.oi[tt].x));
        ov.y = f2bf(oacc[tt][1] + bf2f(R.oi[tt].y));
        ov.z = f2bf(oacc[tt][2] + bf2f(R.oi[tt].z));
        ov.w = f2bf(oacc[tt][3] + bf2f(R.oi[tt].w));
        *(ushortx4*)(o + (size_t)trow * 1024 + h * 64 + vg * 16 + l4 * 4) = ov;
    }
}

__global__ __launch_bounds__(256) void seq_wtrans_kernel(
    const unsigned short* __restrict__ Gt, const unsigned short* __restrict__ LRt,
    const unsigned short* __restrict__ VcT, const float* __restrict__ Wl,
    const unsigned short* __restrict__ Oi, unsigned short* __restrict__ o,
    const float* __restrict__ Wo, unsigned short* __restrict__ wtD)
{
    __shared__ __align__(16) char sarena[4224];
    const int bid = blockIdx.x;
    if (bid >= 128) {
        // -------- W_o transpose path (b_wl dead: prep completed) --------
        float (*tile)[33] = (float (*)[33])sarena;
        const int wb = bid - 128;
        const int tx = threadIdx.x & 31, ty = threadIdx.x >> 5;
        const int n0 = (wb & 31) * 32, k0 = (wb >> 5) * 32;
#pragma unroll
        for (int i = 0; i < 4; ++i)
            tile[ty + i * 8][tx] = Wo[(size_t)(k0 + ty + i * 8) * 1024 + n0 + tx];
        __syncthreads();
#pragma unroll
        for (int i = 0; i < 4; ++i)
            wtD[(size_t)(n0 + ty + i * 8) * 1024 + k0 + tx] = f2bf(tile[tx][ty + i * 8]);
        return;
    }
    if (threadIdx.x >= 64) return;   // seq path: single wave
    unsigned short (*Sst)[80] = (unsigned short (*)[80])sarena;
    const int lane = threadIdx.x & 63;
    const int bh = bid >> 2, vg = bid & 3;
    const int b = bh >> 4, h = bh & 15;
    const int l15 = lane & 15, l4 = lane >> 4;

    const size_t cbase = (size_t)bh * 32;
    const unsigned short* gt = Gt + cbase * 2048;
    const unsigned short* lr = LRt + cbase * 4096;
    const unsigned short* vct = VcT + cbase * 4096;
    const float* wlp = Wl + cbase * 64;
    const unsigned short* oi = Oi + cbase * 2048;

    f32x4 sC[4] = {};
    SeqRegs RA, RB;
    load_chunk(RA, gt, lr, vct, wlp, oi, l15, l4, vg);

    for (int cc = 0; cc < 16; ++cc) {
        const int c0 = cc * 2, c1 = cc * 2 + 1;
        load_chunk(RB, gt + (size_t)c1 * 2048, lr + (size_t)c1 * 4096,
                   vct + (size_t)c1 * 4096, wlp + (size_t)c1 * 64,
                   oi + (size_t)c1 * 2048, l15, l4, vg);
        seq_step(sC, RA, Sst, o, b, h, c0, vg, l15, l4);
        const int c2 = (c1 + 1 < 32) ? c1 + 1 : 31;
        load_chunk(RA, gt + (size_t)c2 * 2048, lr + (size_t)c2 * 4096,
                   vct + (size_t)c2 * 4096, wlp + (size_t)c2 * 64,
                   oi + (size_t)c2 * 2048, l15, l4, vg);
        seq_step(sC, RB, Sst, o, b, h, c1, vg, l15, l4);
    }
}

// ---------------- groupnorm + bonus + gate (bf16 in, bf16 y out) ----------------
__global__ __launch_bounds__(256) void post_kernel(
    const unsigned short* o, const unsigned short* v, const unsigned short* g,
    const float* __restrict__ TB,
    const float* ln_w, const float* ln_b,
    unsigned short* y)
{
    const int gw = (blockIdx.x * blockDim.x + threadIdx.x) >> 6;
    const int lane = threadIdx.x & 63;
    const int row = gw >> 4;
    const int h = gw & 15;
    const int c = h * N_DIM + lane;
    const size_t idx = (size_t)row * C_DIM + c;
    const int b = row >> 10;
    const int t = row & 1023;

    const float oo = bf2f(o[idx]);
    float s1 = oo, s2 = oo * oo;
#pragma unroll
    for (int m = 32; m; m >>= 1) {
        s1 += __shfl_xor(s1, m);
        s2 += __shfl_xor(s2, m);
    }
    const float mu = s1 * (1.0f / 64.0f);
    const float var = s2 * (1.0f / 64.0f) - mu * mu;
    float yv = (oo - mu) * rsqrtf(var + 0.00064f);
    yv = yv * ln_w[c] + ln_b[c];

    yv += TB[(b * 16 + h) * 1024 + t] * bf2f(v[idx]);
    y[idx] = f2bf(yv * bf2f(g[idx]));
}

extern "C" void kernel_launch(void* const* d_in, const int* in_sizes, int n_in,
                              void* d_out, int out_size, void* d_ws, size_t ws_size,
                              hipStream_t stream) {
    (void)in_sizes; (void)n_in; (void)out_size; (void)ws_size;

    const float* residual = (const float*)d_in[0];
    const float* x        = (const float*)d_in[1];
    const float* v_first  = (const float*)d_in[2];
    const float* mr = (const float*)d_in[6];
    const float* mw = (const float*)d_in[7];
    const float* mk = (const float*)d_in[8];
    const float* mv = (const float*)d_in[9];
    const float* ma = (const float*)d_in[10];
    const float* mg = (const float*)d_in[11];
    const float* w0 = (const float*)d_in[12];
    const float* w1 = (const float*)d_in[13];
    const float* w2 = (const float*)d_in[14];
    const float* a0 = (const float*)d_in[15];
    const float* a1 = (const float*)d_in[16];
    const float* a2 = (const float*)d_in[17];
    const float* v0 = (const float*)d_in[18];
    const float* v1 = (const float*)d_in[19];
    const float* v2 = (const float*)d_in[20];
    const float* g1 = (const float*)d_in[21];
    const float* g2 = (const float*)d_in[22];
    const float* k_k = (const float*)d_in[23];
    const float* k_a = (const float*)d_in[24];
    const float* r_k = (const float*)d_in[25];
    const float* W_r = (const float*)d_in[26];
    const float* W_k = (const float*)d_in[27];
    const float* W_v = (const float*)d_in[28];
    const float* W_o = (const float*)d_in[29];
    const float* ln_w = (const float*)d_in[30];
    const float* ln_b = (const float*)d_in[31];

    float* out = (float*)d_out;
    char* wsb = (char*)d_ws;

    // ---- workspace layout (bytes); max end 69,730,304 (proven safe) ----
    unsigned short* xr = (unsigned short*)(wsb + 0);
    unsigned short* xk = (unsigned short*)(wsb + 4194304);
    unsigned short* xv = (unsigned short*)(wsb + 8388608);
    unsigned short* xw = (unsigned short*)(wsb + 12582912);
    unsigned short* xa = (unsigned short*)(wsb + 16777216);
    unsigned short* xg = (unsigned short*)(wsb + 20971520);     // ends 25,165,824
    unsigned short* VcT = (unsigned short*)(wsb + 0);           // bf16 VcT[n][vi], post-s1 (8 MiB)
    unsigned short* Gt = (unsigned short*)(wsb + 16777216);     // over xa
    unsigned short* Oi = (unsigned short*)(wsb + 20971520);     // over xg
    // planar pk components (dense 4 MiB each; all dead after prep)
    unsigned short* b_wl = (unsigned short*)(wsb + 25165824);
    unsigned short* b_k  = (unsigned short*)(wsb + 29360128);
    unsigned short* b_a  = (unsigned short*)(wsb + 33554432);
    unsigned short* b_vg = (unsigned short*)(wsb + 37748736);   // ends 41,943,040
    unsigned short* wtD  = (unsigned short*)(wsb + 25165824);   // 2 MiB over dead b_wl
    unsigned short* y_bf = (unsigned short*)(wsb + 27262976);   // 4 MiB over dead planar
    unsigned short* b_r = (unsigned short*)(wsb + 41943040);
    unsigned short* b_v = (unsigned short*)(wsb + 46137344);
    unsigned short* b_o = (unsigned short*)(wsb + 50331648);
    unsigned short* b_g = (unsigned short*)(wsb + 54525952);
    unsigned short* h_cat = (unsigned short*)(wsb + 58720256);
    unsigned short* wt_a1 = (unsigned short*)(wsb + 60293120);
    unsigned short* wt_v1 = (unsigned short*)(wsb + 60424192);
    unsigned short* wt_g1 = (unsigned short*)(wsb + 60489728);
    unsigned short* wt_a2 = (unsigned short*)(wsb + 60817408);
    unsigned short* wt_v2 = (unsigned short*)(wsb + 60948480);
    unsigned short* wt_g2 = (unsigned short*)(wsb + 61014016);
    unsigned short* wt_w1 = (unsigned short*)(wsb + 61341696);
    unsigned short* wt_w2 = (unsigned short*)(wsb + 61472768);
    unsigned short* wtA = (unsigned short*)(wsb + 61603840);
    unsigned short* wtB = (unsigned short*)(wsb + 63700992);
    unsigned short* wtC = (unsigned short*)(wsb + 65798144);    // ends 67,895,296
    unsigned short* LRt = (unsigned short*)(wsb + 60030976);    // 8 MiB over dead wts
    float* Wl = (float*)(wsb + 68419584);
    float* TB = (float*)(wsb + 68681728);

    const dim3 blk(256);

    // 1) stage0: premix + all weight transposes (concurrent, one launch)
    stage0_kernel<<<dim3(4736), blk, 0, stream>>>(
        x, mr, mk, mv, mw, ma, mg, xr, xk, xv, xw, xa, xg,
        W_k, W_v, W_r, w1, a1, v1, g1, a2, v2, g2, w2,
        wtA, wtB, wtC, wt_w1, wt_a1, wt_v1, wt_g1, wt_a2, wt_v2, wt_g2, wt_w2);

    // 2) stage-1 FUSED: r,k,v (128^2 pipelined) + a1,v1,g1,w1 (64^2 pipelined)
    gemm_s1_kernel<<<dim3(576), blk, 0, stream>>>(
        xr, xk, xv, xw, xa, xg, wtA, wtB, wtC,
        wt_a1, wt_v1, wt_g1, wt_w1, b_r, b_k, b_v, h_cat);

    // 3) stage-2: a2, v2, g2, w2 (dense planar outputs)
    gemm_s2_kernel<<<dim3(64, 32), blk, 0, stream>>>(
        h_cat, wt_a2, wt_v2, wt_g2, wt_w2, b_a, b_vg, b_g, b_wl);

    // 4) chunk prep (grid 1024, 6-barrier version)
    chunk_prep_kernel<<<dim3(1024), blk, 0, stream>>>(
        b_wl, b_k, b_a, b_vg, b_r, b_v, v_first, w0, a0, v0, k_k, k_a, r_k,
        TB, Gt, LRt, VcT, Wl, Oi);

    // 5) sequential chunk scan + W_o transpose (fills idle CUs; b_wl dead)
    seq_wtrans_kernel<<<dim3(1152), blk, 0, stream>>>(
        Gt, LRt, VcT, Wl, Oi, b_o, W_o, wtD);

    // 6) groupnorm + bonus + gate
    post_kernel<<<dim3(8192), blk, 0, stream>>>(
        b_o, b_v, b_g, TB, ln_w, ln_b, y_bf);

    // 7) output projection + residual (128x128 pipelined)
    gemm_final128_kernel<<<dim3(8, 16), blk, 0, stream>>>(y_bf, wtD, residual, out);
}

// Round 24
// 142.275 us; speedup vs baseline: 1.1726x; 1.1726x over previous
//
#include <hip/hip_runtime.h>
#include <math.h>

// Problem constants
#define B_DIM 2
#define T_SEQ 1024
#define C_DIM 1024
#define H_DIM 16
#define N_DIM 64
#define M_ROWS (B_DIM * T_SEQ)   // 2048

// MFMA GEMM tiling (64x64 path, small GEMMs)
#define GBM 64
#define GBN 64
#define GBK 64
#define LDK 88
#define SW(r, c) ((c) ^ (((((r) >> 3) & 3)) << 3))
// 128x128 path: 16-short-granule swizzle on [128][40] tiles
#define SW16(r, c) ((c) ^ ((((r) >> 3) & 1) << 4))

typedef __attribute__((ext_vector_type(8))) short bf16x8;
typedef __attribute__((ext_vector_type(4))) float f32x4;
typedef unsigned short ushortx4 __attribute__((ext_vector_type(4)));
typedef unsigned short ushortx8 __attribute__((ext_vector_type(8)));

__device__ __forceinline__ unsigned short f2bf(float f) {
    unsigned int u = __float_as_uint(f);
    u = (u + 0x7FFFu + ((u >> 16) & 1u)) >> 16;   // RNE
    return (unsigned short)u;
}
__device__ __forceinline__ float bf2f(unsigned short h) {
    return __uint_as_float(((unsigned int)h) << 16);
}
__device__ __forceinline__ float fsigmoid(float x) {
    return 1.0f / (1.0f + __expf(-x));
}
__device__ __forceinline__ float ftanh(float x) {
    const float t = __expf(-2.0f * fabsf(x));
    const float r = (1.0f - t) / (1.0f + t);
    return copysignf(r, x);
}

__device__ __forceinline__ float wred64(float v) {
#pragma unroll
    for (int m = 32; m; m >>= 1) v += __shfl_xor(v, m);
    return v;
}

// ---------------- stage0: premix (1024 blocks) + all weight transposes (3712) -------
__global__ __launch_bounds__(256) void stage0_kernel(
    const float* __restrict__ x,
    const float* mr, const float* mk, const float* mv,
    const float* mw, const float* ma, const float* mg,
    unsigned short* xr, unsigned short* xk, unsigned short* xv,
    unsigned short* xw, unsigned short* xa, unsigned short* xg,
    const float* Wk, const float* Wv, const float* Wr,
    const float* w1p, const float* a1p, const float* v1p, const float* g1p,
    const float* a2p, const float* v2p, const float* g2p, const float* w2p,
    unsigned short* wtA, unsigned short* wtB, unsigned short* wtC,
    unsigned short* wt_w1, unsigned short* wt_a1, unsigned short* wt_v1,
    unsigned short* wt_g1, unsigned short* wt_a2, unsigned short* wt_v2,
    unsigned short* wt_g2, unsigned short* wt_w2)
{
    __shared__ float tile[32][33];
    const int bid0 = blockIdx.x;
    if (bid0 < 1024) {
        // -------- premix path --------
        const int g = bid0 * 256 + threadIdx.x;
        const size_t base = (size_t)g * 8;
        const int row = (int)(base >> 10);
        const int col = (int)(base & 1023);
        const int t_in = row & (T_SEQ - 1);

        const float* xp = x + (size_t)row * C_DIM + col;
        float4 a0 = *(const float4*)xp;
        float4 a1 = *(const float4*)(xp + 4);
        float4 p0 = make_float4(0.f, 0.f, 0.f, 0.f), p1 = p0;
        if (t_in > 0) {
            p0 = *(const float4*)(xp - C_DIM);
            p1 = *(const float4*)(xp - C_DIM + 4);
        }
        const float d0x = p0.x - a0.x, d0y = p0.y - a0.y, d0z = p0.z - a0.z, d0w = p0.w - a0.w;
        const float d1x = p1.x - a1.x, d1y = p1.y - a1.y, d1z = p1.z - a1.z, d1w = p1.w - a1.w;

        const float* ms[6] = {mr, mk, mv, mw, ma, mg};
        unsigned short* outs[6] = {xr, xk, xv, xw, xa, xg};
#pragma unroll
        for (int i = 0; i < 6; ++i) {
            const float4 m0 = *(const float4*)(ms[i] + col);
            const float4 m1 = *(const float4*)(ms[i] + col + 4);
            ushortx8 o;
            o[0] = f2bf(fmaf(d0x, m0.x, a0.x));
            o[1] = f2bf(fmaf(d0y, m0.y, a0.y));
            o[2] = f2bf(fmaf(d0z, m0.z, a0.z));
            o[3] = f2bf(fmaf(d0w, m0.w, a0.w));
            o[4] = f2bf(fmaf(d1x, m1.x, a1.x));
            o[5] = f2bf(fmaf(d1y, m1.y, a1.y));
            o[6] = f2bf(fmaf(d1z, m1.z, a1.z));
            o[7] = f2bf(fmaf(d1w, m1.w, a1.w));
            *(ushortx8*)(outs[i] + base) = o;
        }
        return;
    }
    // -------- transpose path --------
    const int bid = bid0 - 1024;
    const float* W; unsigned short* WT; int K, N, t0;
    if      (bid < 1024) { W = Wk;  WT = wtA;   K = 1024; N = 1024; t0 = 0;    }
    else if (bid < 2048) { W = Wv;  WT = wtB;   K = 1024; N = 1024; t0 = 1024; }
    else if (bid < 3072) { W = Wr;  WT = wtC;   K = 1024; N = 1024; t0 = 2048; }
    else if (bid < 3136) { W = w1p; WT = wt_w1; K = 1024; N = 64;   t0 = 3072; }
    else if (bid < 3200) { W = a1p; WT = wt_a1; K = 1024; N = 64;   t0 = 3136; }
    else if (bid < 3232) { W = v1p; WT = wt_v1; K = 1024; N = 32;   t0 = 3200; }
    else if (bid < 3392) { W = g1p; WT = wt_g1; K = 1024; N = 160;  t0 = 3232; }
    else if (bid < 3456) { W = a2p; WT = wt_a2; K = 64;   N = 1024; t0 = 3392; }
    else if (bid < 3488) { W = v2p; WT = wt_v2; K = 32;   N = 1024; t0 = 3456; }
    else if (bid < 3648) { W = g2p; WT = wt_g2; K = 160;  N = 1024; t0 = 3488; }
    else                 { W = w2p; WT = wt_w2; K = 64;   N = 1024; t0 = 3648; }
    const int lt = bid - t0;
    const int ntx = N >> 5;
    const int n0 = (lt % ntx) * 32;
    const int k0 = (lt / ntx) * 32;
    const int tx = threadIdx.x & 31, ty = threadIdx.x >> 5;
#pragma unroll
    for (int i = 0; i < 4; ++i)
        tile[ty + i * 8][tx] = W[(size_t)(k0 + ty + i * 8) * N + n0 + tx];
    __syncthreads();
#pragma unroll
    for (int i = 0; i < 4; ++i)
        WT[(size_t)(n0 + ty + i * 8) * K + k0 + tx] = f2bf(tile[tx][ty + i * 8]);
}

// ---------------- generic 64x64 MFMA GEMM core (register-prefetch pipelined) -------
__device__ __forceinline__ void gemm_core(
    unsigned short (*As)[LDK], unsigned short (*Bs)[LDK],
    const unsigned short* __restrict__ Aarr, int arow_stride,
    const unsigned short* __restrict__ WT, int K, int Nc, int bn0, int bm0,
    unsigned short* outp, unsigned short* outh, int hoff, int post)
{
    const int tid = threadIdx.x;
    const int lane = tid & 63;
    const int wid = tid >> 6;
    const int wr = wid >> 1, wc = wid & 1;
    const int l15 = lane & 15, l4 = lane >> 4;

    const int ar = tid >> 2;
    const int as = (tid & 3) << 4;
    const int row = bm0 + ar;
    const int brn = tid >> 2;
    const int bks = (tid & 3) << 4;
    const bool bn_ok = (bn0 + brn) < Nc;

    const int ra0 = wr * 32 + l15, ra1 = wr * 32 + 16 + l15;
    const int rb0 = wc * 32 + l15, rb1 = wc * 32 + 16 + l15;

    f32x4 acc[2][2] = {};
    const ushortx8 zz = {0, 0, 0, 0, 0, 0, 0, 0};
    ushortx8 pa0 = zz, pa1 = zz, pb0 = zz, pb1 = zz;

    if (as < K)      pa0 = *(const ushortx8*)(Aarr + (size_t)row * arow_stride + as);
    if (as + 8 < K)  pa1 = *(const ushortx8*)(Aarr + (size_t)row * arow_stride + as + 8);
    if (bn_ok && bks < K)     pb0 = *(const ushortx8*)(WT + (size_t)(bn0 + brn) * K + bks);
    if (bn_ok && bks + 8 < K) pb1 = *(const ushortx8*)(WT + (size_t)(bn0 + brn) * K + bks + 8);

    for (int k0 = 0; k0 < K; k0 += GBK) {
        *(ushortx8*)&As[ar][SW(ar, as)] = pa0;
        *(ushortx8*)&As[ar][SW(ar, as + 8)] = pa1;
        *(ushortx8*)&Bs[brn][SW(brn, bks)] = pb0;
        *(ushortx8*)&Bs[brn][SW(brn, bks + 8)] = pb1;
        __syncthreads();

        const int kn = k0 + GBK;
        if (kn < K) {
            pa0 = zz; pa1 = zz; pb0 = zz; pb1 = zz;
            if (kn + as < K)
                pa0 = *(const ushortx8*)(Aarr + (size_t)row * arow_stride + kn + as);
            if (kn + as + 8 < K)
                pa1 = *(const ushortx8*)(Aarr + (size_t)row * arow_stride + kn + as + 8);
            if (bn_ok && kn + bks < K)
                pb0 = *(const ushortx8*)(WT + (size_t)(bn0 + brn) * K + kn + bks);
            if (bn_ok && kn + bks + 8 < K)
                pb1 = *(const ushortx8*)(WT + (size_t)(bn0 + brn) * K + kn + bks + 8);
        }

#pragma unroll
        for (int ks = 0; ks < 2; ++ks) {
            const int cc = ks * 32 + l4 * 8;
            bf16x8 af0 = *(const bf16x8*)&As[ra0][SW(ra0, cc)];
            bf16x8 af1 = *(const bf16x8*)&As[ra1][SW(ra1, cc)];
            bf16x8 bg0 = *(const bf16x8*)&Bs[rb0][SW(rb0, cc)];
            bf16x8 bg1 = *(const bf16x8*)&Bs[rb1][SW(rb1, cc)];
            acc[0][0] = __builtin_amdgcn_mfma_f32_16x16x32_bf16(af0, bg0, acc[0][0], 0, 0, 0);
            acc[0][1] = __builtin_amdgcn_mfma_f32_16x16x32_bf16(af0, bg1, acc[0][1], 0, 0, 0);
            acc[1][0] = __builtin_amdgcn_mfma_f32_16x16x32_bf16(af1, bg0, acc[1][0], 0, 0, 0);
            acc[1][1] = __builtin_amdgcn_mfma_f32_16x16x32_bf16(af1, bg1, acc[1][1], 0, 0, 0);
        }
        __syncthreads();
    }

#pragma unroll
    for (int fi = 0; fi < 2; ++fi)
#pragma unroll
        for (int fj = 0; fj < 2; ++fj) {
            const int ocol = bn0 + wc * 32 + fj * 16 + l15;
            if (ocol < Nc) {
#pragma unroll
                for (int p = 0; p < 4; ++p) {
                    const int orow = bm0 + wr * 32 + fi * 16 + l4 * 4 + p;
                    float v = acc[fi][fj][p];
                    if (post == 1) v = ftanh(v);
                    else if (post == 2) v = fsigmoid(v);
                    if (outh)
                        outh[(size_t)orow * 320 + hoff + ocol] = f2bf(v);
                    else
                        outp[(size_t)orow * 1024 + ocol] = f2bf(v);
                }
            }
        }
}

// ---------------- 128x128 MFMA GEMM core (K=1024, register-prefetch pipelined) ------
__device__ __forceinline__ void gemm128_core(
    const unsigned short* __restrict__ A,
    const unsigned short* __restrict__ WT,
    int bm0, int bn0,
    unsigned short (*As)[40], unsigned short (*Bs)[40],
    f32x4 (*acc)[4])
{
    const int tid = threadIdx.x;
    const int lane = tid & 63;
    const int w = tid >> 6;
    const int wr = w >> 1, wc = w & 1;
    const int l15 = lane & 15, l4 = lane >> 4;
    const int sr = tid >> 1;
    const int sc = (tid & 1) << 4;
    const int ssc = SW16(sr, sc);

    const unsigned short* ap = A + (size_t)(bm0 + sr) * 1024 + sc;
    const unsigned short* bp = WT + (size_t)(bn0 + sr) * 1024 + sc;

    ushortx8 av0 = *(const ushortx8*)(ap);
    ushortx8 av1 = *(const ushortx8*)(ap + 8);
    ushortx8 bv0 = *(const ushortx8*)(bp);
    ushortx8 bv1 = *(const ushortx8*)(bp + 8);

    for (int k0 = 0; k0 < 1024; k0 += 32) {
        *(ushortx8*)&As[sr][ssc] = av0;
        *(ushortx8*)&As[sr][ssc + 8] = av1;
        *(ushortx8*)&Bs[sr][ssc] = bv0;
        *(ushortx8*)&Bs[sr][ssc + 8] = bv1;
        __syncthreads();

        const int kn = (k0 + 32 < 1024) ? k0 + 32 : k0;   // redundant tail reload
        av0 = *(const ushortx8*)(ap + kn);
        av1 = *(const ushortx8*)(ap + kn + 8);
        bv0 = *(const ushortx8*)(bp + kn);
        bv1 = *(const ushortx8*)(bp + kn + 8);

        bf16x8 af[4], bg[4];
#pragma unroll
        for (int f = 0; f < 4; ++f) {
            const int ra = wr * 64 + f * 16 + l15;
            const int rb = wc * 64 + f * 16 + l15;
            af[f] = *(const bf16x8*)&As[ra][SW16(ra, l4 * 8)];
            bg[f] = *(const bf16x8*)&Bs[rb][SW16(rb, l4 * 8)];
        }
#pragma unroll
        for (int fi = 0; fi < 4; ++fi)
#pragma unroll
            for (int fj = 0; fj < 4; ++fj)
                acc[fi][fj] = __builtin_amdgcn_mfma_f32_16x16x32_bf16(
                    af[fi], bg[fj], acc[fi][fj], 0, 0, 0);
        __syncthreads();
    }
}

// ---------------- stage-1 FUSED: 384 big-path + 192 small-path blocks ----------------
__global__ __launch_bounds__(256) void gemm_s1_kernel(
    const unsigned short* xr, const unsigned short* xk, const unsigned short* xv,
    const unsigned short* xw, const unsigned short* xa, const unsigned short* xg,
    const unsigned short* wtA, const unsigned short* wtB, const unsigned short* wtC,
    const unsigned short* wt_a1, const unsigned short* wt_v1,
    const unsigned short* wt_g1, const unsigned short* wt_w1,
    unsigned short* b_r, unsigned short* b_k, unsigned short* b_v,
    unsigned short* h_cat)
{
    __shared__ __align__(16) char sarena[22528];
    const int bid = blockIdx.x;
    if (bid < 384) {
        unsigned short (*As)[40] = (unsigned short (*)[40])sarena;
        unsigned short (*Bs)[40] = (unsigned short (*)[40])(sarena + 10240);
        const int g = bid >> 7;
        const int sub = bid & 127;
        const int bn0 = (sub & 7) * 128;
        const int bm0 = (sub >> 3) * 128;
        const unsigned short* A = (g == 0) ? xr : (g == 1) ? xk : xv;
        const unsigned short* WT = (g == 0) ? wtC : (g == 1) ? wtA : wtB;
        unsigned short* O = (g == 0) ? b_r : (g == 1) ? b_k : b_v;

        f32x4 acc[4][4] = {};
        gemm128_core(A, WT, bm0, bn0, As, Bs, acc);

        const int lane = threadIdx.x & 63;
        const int w = threadIdx.x >> 6;
        const int wr = w >> 1, wc = w & 1;
        const int l15 = lane & 15, l4 = lane >> 4;
#pragma unroll
        for (int fi = 0; fi < 4; ++fi)
#pragma unroll
            for (int fj = 0; fj < 4; ++fj) {
                const int ocol = bn0 + wc * 64 + fj * 16 + l15;
#pragma unroll
                for (int p = 0; p < 4; ++p) {
                    const int orow = bm0 + wr * 64 + fi * 16 + l4 * 4 + p;
                    O[(size_t)orow * 1024 + ocol] = f2bf(acc[fi][fj][p]);
                }
            }
    } else {
        unsigned short (*As)[LDK] = (unsigned short (*)[LDK])sarena;
        unsigned short (*Bs)[LDK] = (unsigned short (*)[LDK])(sarena + 11264);
        const int sid = bid - 384;
        const int nt = sid % 6;
        const int bm0 = (sid / 6) * 64;
        const unsigned short* A; const unsigned short* WT;
        int Nc, nb = 0, hoff, post = 0;
        if (nt == 0)      { A = xa; WT = wt_a1; hoff = 0;   Nc = 64; }
        else if (nt == 1) { A = xv; WT = wt_v1; hoff = 64;  Nc = 32; }
        else if (nt < 5)  { A = xg; WT = wt_g1; hoff = 96;  Nc = 160; nb = nt - 2; post = 2; }
        else              { A = xw; WT = wt_w1; hoff = 256; Nc = 64; post = 1; }
        gemm_core(As, Bs, A, 1024, WT, 1024, Nc, nb * 64, bm0,
                  nullptr, h_cat, hoff, post);
    }
}

// ---------------- stage-2: 4 GEMMs in one launch (A = h_cat, dense planar outs) -----
__global__ __launch_bounds__(256) void gemm_s2_kernel(
    const unsigned short* __restrict__ h_cat,
    const unsigned short* wt_a2, const unsigned short* wt_v2,
    const unsigned short* wt_g2, const unsigned short* wt_w2,
    unsigned short* b_a, unsigned short* b_vg, unsigned short* b_g,
    unsigned short* b_wl)
{
    __shared__ unsigned short As[GBM][LDK];
    __shared__ unsigned short Bs[GBN][LDK];
    const int g = blockIdx.x >> 4;
    const int nb = blockIdx.x & 15;
    const int bm0 = blockIdx.y * GBM;
    const unsigned short* WT;
    unsigned short* outp; int K, aoff;
    if      (g == 0) { WT = wt_a2; K = 64;  aoff = 0;   outp = b_a; }
    else if (g == 1) { WT = wt_v2; K = 32;  aoff = 64;  outp = b_vg; }
    else if (g == 2) { WT = wt_g2; K = 160; aoff = 96;  outp = b_g; }
    else             { WT = wt_w2; K = 64;  aoff = 256; outp = b_wl; }
    gemm_core(As, Bs, h_cat + aoff, 320, WT, K, 1024, nb * 64, bm0,
              outp, nullptr, 0, 0);
}

// ---------------- final GEMM (128x128): out = y_bf @ W_o + residual (f32 out) -------
__global__ __launch_bounds__(256) void gemm_final128_kernel(
    const unsigned short* __restrict__ Y, const unsigned short* __restrict__ WT,
    const float* __restrict__ addend, float* __restrict__ out)
{
    __shared__ unsigned short As[128][40];
    __shared__ unsigned short Bs[128][40];
    const int bn0 = blockIdx.x * 128;
    const int bm0 = blockIdx.y * 128;

    f32x4 acc[4][4] = {};
    gemm128_core(Y, WT, bm0, bn0, As, Bs, acc);

    const int lane = threadIdx.x & 63;
    const int w = threadIdx.x >> 6;
    const int wr = w >> 1, wc = w & 1;
    const int l15 = lane & 15, l4 = lane >> 4;
#pragma unroll
    for (int fi = 0; fi < 4; ++fi)
#pragma unroll
        for (int fj = 0; fj < 4; ++fj) {
            const int ocol = bn0 + wc * 64 + fj * 16 + l15;
#pragma unroll
            for (int p = 0; p < 4; ++p) {
                const int orow = bm0 + wr * 64 + fi * 16 + l4 * 4 + p;
                out[(size_t)orow * 1024 + ocol] =
                    acc[fi][fj][p] + addend[(size_t)orow * 1024 + ocol];
            }
        }
}

// ---------------- chunked-scan PREP (single chunk/block, fixed LDS overlays) --------
// LDS layout (53,120 B; 3 blocks/CU):
//  0      tB[32][72]      4608
//  4608   tK[32][72]      4608
//  9216   tR[32][72]      4608
//  13824  tBT[64][40]     5120
//  18944  VlT[64][40]     5120
//  24064  egT[32][40]     2560
//  26624  W32s[32][66]f32 8448 (dead after C) | cg[32][33] @26624 (D..F) | DhB[32][40] @26624 (F2..)
//  30848                      | dg[32][33] @30848 (D..F2-read) | fT[32][40] @30848 (G-a..)
//  35072  fg[32][33]      4224
//  39296  tA[32][72]      4608 (dead after F) | ZB[64][40] @39296 (F2..; full 5120, ends 44416)
//  44416  EWZ f32         8448 (A..F2) | KtT[64][40] @44416 (G-a..)
//  52864  w31s            256
__global__ __launch_bounds__(256) void chunk_prep_kernel(
    const unsigned short* __restrict__ b_wl, const unsigned short* __restrict__ b_k,
    const unsigned short* __restrict__ b_a, const unsigned short* __restrict__ b_vg,
    const unsigned short* __restrict__ b_r,
    unsigned short* __restrict__ b_v,
    const float* __restrict__ v_first,
    const float* w0, const float* a0, const float* v0,
    const float* k_k, const float* k_a, const float* r_k,
    float* __restrict__ TB,
    unsigned short* __restrict__ Gt, unsigned short* __restrict__ LRt,
    unsigned short* __restrict__ VcT, float* __restrict__ Wl,
    unsigned short* __restrict__ Oi)
{
    __shared__ __align__(16) char smem[53120];
    unsigned short (*tB)[72]  = (unsigned short (*)[72])(smem + 0);
    unsigned short (*tK)[72]  = (unsigned short (*)[72])(smem + 4608);
    unsigned short (*tR)[72]  = (unsigned short (*)[72])(smem + 9216);
    unsigned short (*tBT)[40] = (unsigned short (*)[40])(smem + 13824);
    unsigned short (*VlT)[40] = (unsigned short (*)[40])(smem + 18944);
    unsigned short (*egT)[40] = (unsigned short (*)[40])(smem + 24064);
    float (*W32s)[66]         = (float (*)[66])(smem + 26624);
    float (*cg)[33]           = (float (*)[33])(smem + 26624);
    unsigned short (*DhB)[40] = (unsigned short (*)[40])(smem + 26624);
    float (*dg)[33]           = (float (*)[33])(smem + 30848);
    unsigned short (*fT)[40]  = (unsigned short (*)[40])(smem + 30848);
    float (*fg)[33]           = (float (*)[33])(smem + 35072);
    unsigned short (*tA)[72]  = (unsigned short (*)[72])(smem + 39296);
    unsigned short (*ZB)[40]  = (unsigned short (*)[40])(smem + 39296);   // full 5120B
    float* EWZ                = (float*)(smem + 44416);
    unsigned short (*KtT)[40] = (unsigned short (*)[40])(smem + 44416);
    float* w31s               = (float*)(smem + 52864);

    const int tid = threadIdx.x;
    const int lane = tid & 63;
    const int w = tid >> 6;
    const int l15 = lane & 15, l4 = lane >> 4;
    const int bhc = blockIdx.x;
    const int bh = bhc >> 5, ck = bhc & 31;
    const int b = bh >> 4, h = bh & 15;
    const int cglob = h * 64 + lane;

    // ---- Phase A: planar loads + stage3 elementwise (fast-exp) ----
    const float kkc = k_k[cglob], kac = k_a[cglob];
    const float a0c = a0[cglob], v0c = v0[cglob];
    const float w0c = w0[cglob], rkc = r_k[cglob];
#pragma unroll
    for (int q = 0; q < 8; ++q) {
        const int tq = w * 8 + q;
        const int row = b * 1024 + ck * 32 + tq;
        const size_t gi = (size_t)row * 1024 + cglob;
        const float kl = bf2f(b_k[gi]);
        const float kkv = kl * kkc;
        const float ss = wred64(kkv * kkv);
        const float kkn = kkv / fmaxf(sqrtf(ss), 1e-12f);
        const float a = fsigmoid(a0c + bf2f(b_a[gi]));
        const float u = w0c + bf2f(b_wl[gi]);
        const float lnw = -__logf(1.0f + __expf(-u)) - 0.5f;
        const float ew = __expf(-__expf(lnw));
        const float sv = fsigmoid(v0c + bf2f(b_vg[gi]));
        const float vl = bf2f(b_v[gi]);
        const float v = fmaf(v_first[gi] - vl, sv, vl);
        const float ko = kl * (1.0f + (a - 1.0f) * kac);
        const unsigned short rbf = b_r[gi];
        const float r1f = bf2f(rbf);
        const unsigned short vbf = f2bf(v);
        b_v[gi] = vbf;

        const float t3 = wred64(r1f * ko * rkc);
        if (lane == 0) TB[bh * 1024 + ck * 32 + tq] = t3;

        EWZ[tq * 64 + lane] = ew;
        tA[tq][lane] = f2bf(-kkn);
        tB[tq][lane] = f2bf(kkn * a);
        tK[tq][lane] = f2bf(ko);
        tR[tq][lane] = rbf;
        VlT[lane][tq] = vbf;
    }
    __syncthreads();

    // ---- Phase B: decay cumprods (wave 0) ----
    if (w == 0) {
        float run = 1.0f;
        for (int t = 0; t < 32; ++t) {
            run *= EWZ[t * 64 + lane];
            W32s[t][lane] = run;
        }
    }
    __syncthreads();

    // ---- Phase C: tildes in place + tBT; save W31 before D overwrites ----
#pragma unroll
    for (int q = 0; q < 8; ++q) {
        const int tq = w * 8 + q;
        const float Wt = W32s[tq][lane];
        const float Wm1 = tq ? W32s[tq - 1][lane] : 1.0f;
        const float iw = 1.0f / Wt;
        tA[tq][lane] = f2bf(bf2f(tA[tq][lane]) * Wm1);
        const unsigned short tb = f2bf(bf2f(tB[tq][lane]) * iw);
        tB[tq][lane] = tb;
        tBT[lane][tq] = tb;
        tK[tq][lane] = f2bf(bf2f(tK[tq][lane]) * iw);
        tR[tq][lane] = f2bf(bf2f(tR[tq][lane]) * Wt);
    }
    if (tid < 64) w31s[tid] = W32s[31][tid];
    __syncthreads();

    // ---- Phase D: four 32x32 Grams via MFMA (one per wave) ----
    {
        const unsigned short (*Am)[72] = (w == 0 || w == 2) ? tB : tK;
        const unsigned short (*Bm)[72] = (w < 2) ? tA : tR;
        f32x4 gacc[2][2] = {};
#pragma unroll
        for (int kh = 0; kh < 2; ++kh) {
            const int cc = kh * 32 + l4 * 8;
            bf16x8 ax0 = *(const bf16x8*)&Am[l15][cc];
            bf16x8 ax1 = *(const bf16x8*)&Am[16 + l15][cc];
            bf16x8 bx0 = *(const bf16x8*)&Bm[l15][cc];
            bf16x8 bx1 = *(const bf16x8*)&Bm[16 + l15][cc];
            gacc[0][0] = __builtin_amdgcn_mfma_f32_16x16x32_bf16(ax0, bx0, gacc[0][0], 0, 0, 0);
            gacc[0][1] = __builtin_amdgcn_mfma_f32_16x16x32_bf16(ax0, bx1, gacc[0][1], 0, 0, 0);
            gacc[1][0] = __builtin_amdgcn_mfma_f32_16x16x32_bf16(ax1, bx0, gacc[1][0], 0, 0, 0);
            gacc[1][1] = __builtin_amdgcn_mfma_f32_16x16x32_bf16(ax1, bx1, gacc[1][1], 0, 0, 0);
        }
#pragma unroll
        for (int mt = 0; mt < 2; ++mt)
#pragma unroll
            for (int nt = 0; nt < 2; ++nt) {
                const int col = nt * 16 + l15;
                if (w == 2) {
                    ushortx4 st;
#pragma unroll
                    for (int p = 0; p < 4; ++p) st[p] = f2bf(gacc[mt][nt][p]);
                    *(ushortx4*)&egT[col][mt * 16 + l4 * 4] = st;
                } else {
#pragma unroll
                    for (int p = 0; p < 4; ++p) {
                        const int rw = mt * 16 + l4 * 4 + p;
                        if (w == 0) cg[rw][col] = gacc[mt][nt][p];
                        else if (w == 1) dg[rw][col] = gacc[mt][nt][p];
                        else fg[rw][col] = gacc[mt][nt][p];
                    }
                }
            }
    }
    __syncthreads();

    // ---- Phase E: zero invalid triangles ----
#pragma unroll
    for (int p = 0; p < 4; ++p) {
        const int idx = tid * 4 + p;
        const int r_ = idx >> 5, c_ = idx & 31;
        if (r_ >= c_) cg[r_][c_] = 0.0f;
        if (c_ <= r_) dg[r_][c_] = 0.0f;
        if (r_ > c_) fg[r_][c_] = 0.0f;
        if (c_ > r_) egT[r_][c_] = 0;
    }
    __syncthreads();

    // ---- Phase F: triangular recurrences, register-resident prefix ----
    if (w == 0) {
        float z[32];
#pragma unroll
        for (int i = 0; i < 32; ++i) {
            float v0_ = bf2f(tA[i][lane]), v1_ = 0.0f, v2_ = 0.0f, v3_ = 0.0f;
#pragma unroll
            for (int j = 0; j < 32; ++j) {
                if (j < i) {
                    const float c_ = cg[j][i];
                    if ((j & 3) == 0)      v0_ = fmaf(c_, z[j], v0_);
                    else if ((j & 3) == 1) v1_ = fmaf(c_, z[j], v1_);
                    else if ((j & 3) == 2) v2_ = fmaf(c_, z[j], v2_);
                    else                   v3_ = fmaf(c_, z[j], v3_);
                }
            }
            z[i] = (v0_ + v1_) + (v2_ + v3_);
        }
#pragma unroll
        for (int i = 0; i < 32; ++i)
            EWZ[lane * 33 + i] = z[i];
    } else if (w == 1 && lane < 32) {
        float dh[32];
#pragma unroll
        for (int t = 0; t < 32; ++t) {
            float v0_ = dg[lane][t], v1_ = 0.0f, v2_ = 0.0f, v3_ = 0.0f;
#pragma unroll
            for (int j = 0; j < 32; ++j) {
                if (j < t) {
                    const float c_ = cg[j][t];
                    if ((j & 3) == 0)      v0_ = fmaf(c_, dh[j], v0_);
                    else if ((j & 3) == 1) v1_ = fmaf(c_, dh[j], v1_);
                    else if ((j & 3) == 2) v2_ = fmaf(c_, dh[j], v2_);
                    else                   v3_ = fmaf(c_, dh[j], v3_);
                }
            }
            dh[t] = (v0_ + v1_) + (v2_ + v3_);
        }
#pragma unroll
        for (int t = 0; t < 32; ++t)
            dg[lane][t] = dh[t];
    }
    __syncthreads();

    // ---- Phase F2: bf16 copies (DhB over cg; ZB over tA, full slot) ----
#pragma unroll
    for (int p = 0; p < 4; ++p) {
        const int idx = tid * 4 + p;
        DhB[idx >> 5][idx & 31] = f2bf(dg[idx >> 5][idx & 31]);
    }
#pragma unroll
    for (int p = 0; p < 8; ++p) {
        const int idx = tid * 8 + p;
        ZB[idx >> 5][idx & 31] = f2bf(EWZ[(idx >> 5) * 33 + (idx & 31)]);
    }
    __syncthreads();

    const size_t cb2048 = (size_t)bhc * 2048;
    const size_t cb4096 = (size_t)bhc * 4096;

    // ---- Phase G-a ----
    if (w == 0) {
#pragma unroll
        for (int mt = 0; mt < 2; ++mt)
#pragma unroll
            for (int nt = 0; nt < 2; ++nt) {
                f32x4 cacc;
#pragma unroll
                for (int p = 0; p < 4; ++p) cacc[p] = fg[mt * 16 + l4 * 4 + p][nt * 16 + l15];
                bf16x8 ax = *(const bf16x8*)&DhB[mt * 16 + l15][l4 * 8];
                bf16x8 bx = *(const bf16x8*)&egT[nt * 16 + l15][l4 * 8];
                cacc = __builtin_amdgcn_mfma_f32_16x16x32_bf16(ax, bx, cacc, 0, 0, 0);
                ushortx4 st;
#pragma unroll
                for (int p = 0; p < 4; ++p) st[p] = f2bf(cacc[p]);
                *(ushortx4*)&fT[nt * 16 + l15][mt * 16 + l4 * 4] = st;
            }
    } else if (w == 1) {
#pragma unroll
        for (int mt = 0; mt < 2; ++mt)
#pragma unroll
            for (int nt = 0; nt < 4; ++nt) {
                bf16x8 ax = *(const bf16x8*)&DhB[mt * 16 + l15][l4 * 8];
                bf16x8 bx = *(const bf16x8*)&tBT[nt * 16 + l15][l4 * 8];
                f32x4 cacc = {};
                cacc = __builtin_amdgcn_mfma_f32_16x16x32_bf16(ax, bx, cacc, 0, 0, 0);
                const int col = nt * 16 + l15;
                const float w31c = w31s[col];
                ushortx4 st;
#pragma unroll
                for (int p = 0; p < 4; ++p) {
                    const int rw = mt * 16 + l4 * 4 + p;
                    st[p] = f2bf((cacc[p] + bf2f(tK[rw][col])) * w31c);
                }
                *(ushortx4*)&KtT[col][mt * 16 + l4 * 4] = st;
            }
    } else if (w == 2) {
#pragma unroll
        for (int mt = 0; mt < 4; ++mt)
#pragma unroll
            for (int nt = 0; nt < 4; ++nt) {
                bf16x8 ax = *(const bf16x8*)&tBT[mt * 16 + l15][l4 * 8];
                bf16x8 bx = *(const bf16x8*)&ZB[nt * 16 + l15][l4 * 8];
                f32x4 cacc = {};
                cacc = __builtin_amdgcn_mfma_f32_16x16x32_bf16(ax, bx, cacc, 0, 0, 0);
                const int kcol = nt * 16 + l15;
#pragma unroll
                for (int p = 0; p < 4; ++p) {
                    const int n_ = mt * 16 + l4 * 4 + p;
                    LRt[cb4096 + n_ * 64 + kcol] = f2bf(cacc[p] * w31s[n_]);
                }
            }
    } else {
#pragma unroll
        for (int mt = 0; mt < 2; ++mt)
#pragma unroll
            for (int nt = 0; nt < 4; ++nt) {
                bf16x8 ax = *(const bf16x8*)&egT[mt * 16 + l15][l4 * 8];
                bf16x8 bx = *(const bf16x8*)&ZB[nt * 16 + l15][l4 * 8];
                f32x4 cacc = {};
                cacc = __builtin_amdgcn_mfma_f32_16x16x32_bf16(ax, bx, cacc, 0, 0, 0);
                const int ncol = nt * 16 + l15;
#pragma unroll
                for (int p = 0; p < 4; ++p) {
                    const int t_ = mt * 16 + l4 * 4 + p;
                    Gt[cb2048 + t_ * 64 + ncol] = f2bf(cacc[p] + bf2f(tR[t_][ncol]));
                }
            }
    }
    __syncthreads();

    // ---- Phase G-b ----
    if (w < 2) {
#pragma unroll
        for (int mt = 0; mt < 2; ++mt)
#pragma unroll
            for (int ntl = 0; ntl < 2; ++ntl) {
                const int nt = w * 2 + ntl;
                bf16x8 ax = *(const bf16x8*)&fT[mt * 16 + l15][l4 * 8];
                bf16x8 bx = *(const bf16x8*)&VlT[nt * 16 + l15][l4 * 8];
                f32x4 cacc = {};
                cacc = __builtin_amdgcn_mfma_f32_16x16x32_bf16(ax, bx, cacc, 0, 0, 0);
                const int vcol = nt * 16 + l15;
#pragma unroll
                for (int p = 0; p < 4; ++p) {
                    const int t_ = mt * 16 + l4 * 4 + p;
                    Oi[cb2048 + t_ * 64 + vcol] = f2bf(cacc[p]);
                }
            }
    } else {
#pragma unroll
        for (int mtl = 0; mtl < 2; ++mtl)
#pragma unroll
            for (int nt = 0; nt < 4; ++nt) {
                const int mt = (w - 2) * 2 + mtl;
                bf16x8 ax = *(const bf16x8*)&VlT[mt * 16 + l15][l4 * 8];
                bf16x8 bx = *(const bf16x8*)&KtT[nt * 16 + l15][l4 * 8];
                f32x4 cacc = {};
                cacc = __builtin_amdgcn_mfma_f32_16x16x32_bf16(ax, bx, cacc, 0, 0, 0);
                const int ncol = nt * 16 + l15;
                ushortx4 st;
#pragma unroll
                for (int p = 0; p < 4; ++p) st[p] = f2bf(cacc[p]);
                *(ushortx4*)&VcT[cb4096 + (size_t)ncol * 64 + mt * 16 + l4 * 4] = st;
            }
    }
    if (tid < 64) Wl[(size_t)bhc * 64 + tid] = w31s[tid];
}

// ---------------- chunked-scan SEQ (128 blocks) + W_o transpose (1024 blocks) -------
struct SeqRegs {
    bf16x8 g[4];
    bf16x8 lr[8];
    ushortx4 vc[4];
    float wl[4];
    ushortx4 oi[2];
};

__device__ __forceinline__ void load_chunk(
    SeqRegs& R,
    const unsigned short* __restrict__ gt, const unsigned short* __restrict__ lr,
    const unsigned short* __restrict__ vct, const float* __restrict__ wlp,
    const unsigned short* __restrict__ oi, int l15, int l4, int vg)
{
#pragma unroll
    for (int tt = 0; tt < 2; ++tt) {
        R.g[tt * 2 + 0] = *(const bf16x8*)&gt[(tt * 16 + l15) * 64 + l4 * 8];
        R.g[tt * 2 + 1] = *(const bf16x8*)&gt[(tt * 16 + l15) * 64 + 32 + l4 * 8];
        R.oi[tt] = *(const ushortx4*)&oi[(tt * 16 + l15) * 64 + vg * 16 + l4 * 4];
    }
#pragma unroll
    for (int nt = 0; nt < 4; ++nt) {
        R.lr[nt * 2 + 0] = *(const bf16x8*)&lr[(nt * 16 + l15) * 64 + l4 * 8];
        R.lr[nt * 2 + 1] = *(const bf16x8*)&lr[(nt * 16 + l15) * 64 + 32 + l4 * 8];
        R.vc[nt] = *(const ushortx4*)&vct[(nt * 16 + l15) * 64 + vg * 16 + l4 * 4];
        R.wl[nt] = wlp[nt * 16 + l15];
    }
}

__device__ __forceinline__ void seq_step(
    f32x4* sC, const SeqRegs& R, unsigned short (*Sst)[80],
    unsigned short* __restrict__ o, int b, int h, int c, int vg, int l15, int l4)
{
#pragma unroll
    for (int nt = 0; nt < 4; ++nt)
#pragma unroll
        for (int p = 0; p < 4; ++p)
            Sst[l4 * 4 + p][nt * 16 + l15] = f2bf(sC[nt][p]);
    __builtin_amdgcn_wave_barrier();
    bf16x8 a0 = *(const bf16x8*)&Sst[l15][l4 * 8];
    bf16x8 a1 = *(const bf16x8*)&Sst[l15][32 + l4 * 8];
    __builtin_amdgcn_wave_barrier();

    f32x4 oacc[2] = {};
#pragma unroll
    for (int tt = 0; tt < 2; ++tt) {
        oacc[tt] = __builtin_amdgcn_mfma_f32_16x16x32_bf16(a0, R.g[tt * 2 + 0], oacc[tt], 0, 0, 0);
        oacc[tt] = __builtin_amdgcn_mfma_f32_16x16x32_bf16(a1, R.g[tt * 2 + 1], oacc[tt], 0, 0, 0);
    }
    f32x4 lac[4] = {};
#pragma unroll
    for (int nt = 0; nt < 4; ++nt) {
        lac[nt] = __builtin_amdgcn_mfma_f32_16x16x32_bf16(a0, R.lr[nt * 2 + 0], lac[nt], 0, 0, 0);
        lac[nt] = __builtin_amdgcn_mfma_f32_16x16x32_bf16(a1, R.lr[nt * 2 + 1], lac[nt], 0, 0, 0);
    }

#pragma unroll
    for (int nt = 0; nt < 4; ++nt) {
        const float wlv = R.wl[nt];
#pragma unroll
        for (int p = 0; p < 4; ++p)
            sC[nt][p] = fmaf(sC[nt][p], wlv, lac[nt][p] + bf2f(R.vc[nt][p]));
    }

#pragma unroll
    for (int tt = 0; tt < 2; ++tt) {
        const int trow = b * 1024 + c * 32 + tt * 16 + l15;
        ushortx4 ov;
        ov.x = f2bf(oacc[tt][0] + bf2f(R.oi[tt].x));
        ov.y = f2bf(oacc[tt][1] + bf2f(R.oi[tt].y));
        ov.z = f2bf(oacc[tt][2] + bf2f(R.oi[tt].z));
        ov.w = f2bf(oacc[tt][3] + bf2f(R.oi[tt].w));
        *(ushortx4*)(o + (size_t)trow * 1024 + h * 64 + vg * 16 + l4 * 4) = ov;
    }
}

__global__ __launch_bounds__(256) void seq_wtrans_kernel(
    const unsigned short* __restrict__ Gt, const unsigned short* __restrict__ LRt,
    const unsigned short* __restrict__ VcT, const float* __restrict__ Wl,
    const unsigned short* __restrict__ Oi, unsigned short* __restrict__ o,
    const float* __restrict__ Wo, unsigned short* __restrict__ wtD)
{
    __shared__ __align__(16) char sarena[4224];
    const int bid = blockIdx.x;
    if (bid >= 128) {
        // -------- W_o transpose path (b_wl dead: prep completed) --------
        float (*tile)[33] = (float (*)[33])sarena;
        const int wb = bid - 128;
        const int tx = threadIdx.x & 31, ty = threadIdx.x >> 5;
        const int n0 = (wb & 31) * 32, k0 = (wb >> 5) * 32;
#pragma unroll
        for (int i = 0; i < 4; ++i)
            tile[ty + i * 8][tx] = Wo[(size_t)(k0 + ty + i * 8) * 1024 + n0 + tx];
        __syncthreads();
#pragma unroll
        for (int i = 0; i < 4; ++i)
            wtD[(size_t)(n0 + ty + i * 8) * 1024 + k0 + tx] = f2bf(tile[tx][ty + i * 8]);
        return;
    }
    if (threadIdx.x >= 64) return;   // seq path: single wave
    unsigned short (*Sst)[80] = (unsigned short (*)[80])sarena;
    const int lane = threadIdx.x & 63;
    const int bh = bid >> 2, vg = bid & 3;
    const int b = bh >> 4, h = bh & 15;
    const int l15 = lane & 15, l4 = lane >> 4;

    const size_t cbase = (size_t)bh * 32;
    const unsigned short* gt = Gt + cbase * 2048;
    const unsigned short* lr = LRt + cbase * 4096;
    const unsigned short* vct = VcT + cbase * 4096;
    const float* wlp = Wl + cbase * 64;
    const unsigned short* oi = Oi + cbase * 2048;

    f32x4 sC[4] = {};
    SeqRegs RA, RB;
    load_chunk(RA, gt, lr, vct, wlp, oi, l15, l4, vg);

    for (int cc = 0; cc < 16; ++cc) {
        const int c0 = cc * 2, c1 = cc * 2 + 1;
        load_chunk(RB, gt + (size_t)c1 * 2048, lr + (size_t)c1 * 4096,
                   vct + (size_t)c1 * 4096, wlp + (size_t)c1 * 64,
                   oi + (size_t)c1 * 2048, l15, l4, vg);
        seq_step(sC, RA, Sst, o, b, h, c0, vg, l15, l4);
        const int c2 = (c1 + 1 < 32) ? c1 + 1 : 31;
        load_chunk(RA, gt + (size_t)c2 * 2048, lr + (size_t)c2 * 4096,
                   vct + (size_t)c2 * 4096, wlp + (size_t)c2 * 64,
                   oi + (size_t)c2 * 2048, l15, l4, vg);
        seq_step(sC, RB, Sst, o, b, h, c1, vg, l15, l4);
    }
}

// ---------------- groupnorm + bonus + gate (bf16 in, bf16 y out) ----------------
__global__ __launch_bounds__(256) void post_kernel(
    const unsigned short* o, const unsigned short* v, const unsigned short* g,
    const float* __restrict__ TB,
    const float* ln_w, const float* ln_b,
    unsigned short* y)
{
    const int gw = (blockIdx.x * blockDim.x + threadIdx.x) >> 6;
    const int lane = threadIdx.x & 63;
    const int row = gw >> 4;
    const int h = gw & 15;
    const int c = h * N_DIM + lane;
    const size_t idx = (size_t)row * C_DIM + c;
    const int b = row >> 10;
    const int t = row & 1023;

    const float oo = bf2f(o[idx]);
    float s1 = oo, s2 = oo * oo;
#pragma unroll
    for (int m = 32; m; m >>= 1) {
        s1 += __shfl_xor(s1, m);
        s2 += __shfl_xor(s2, m);
    }
    const float mu = s1 * (1.0f / 64.0f);
    const float var = s2 * (1.0f / 64.0f) - mu * mu;
    float yv = (oo - mu) * rsqrtf(var + 0.00064f);
    yv = yv * ln_w[c] + ln_b[c];

    yv += TB[(b * 16 + h) * 1024 + t] * bf2f(v[idx]);
    y[idx] = f2bf(yv * bf2f(g[idx]));
}

extern "C" void kernel_launch(void* const* d_in, const int* in_sizes, int n_in,
                              void* d_out, int out_size, void* d_ws, size_t ws_size,
                              hipStream_t stream) {
    (void)in_sizes; (void)n_in; (void)out_size; (void)ws_size;

    const float* residual = (const float*)d_in[0];
    const float* x        = (const float*)d_in[1];
    const float* v_first  = (const float*)d_in[2];
    const float* mr = (const float*)d_in[6];
    const float* mw = (const float*)d_in[7];
    const float* mk = (const float*)d_in[8];
    const float* mv = (const float*)d_in[9];
    const float* ma = (const float*)d_in[10];
    const float* mg = (const float*)d_in[11];
    const float* w0 = (const float*)d_in[12];
    const float* w1 = (const float*)d_in[13];
    const float* w2 = (const float*)d_in[14];
    const float* a0 = (const float*)d_in[15];
    const float* a1 = (const float*)d_in[16];
    const float* a2 = (const float*)d_in[17];
    const float* v0 = (const float*)d_in[18];
    const float* v1 = (const float*)d_in[19];
    const float* v2 = (const float*)d_in[20];
    const float* g1 = (const float*)d_in[21];
    const float* g2 = (const float*)d_in[22];
    const float* k_k = (const float*)d_in[23];
    const float* k_a = (const float*)d_in[24];
    const float* r_k = (const float*)d_in[25];
    const float* W_r = (const float*)d_in[26];
    const float* W_k = (const float*)d_in[27];
    const float* W_v = (const float*)d_in[28];
    const float* W_o = (const float*)d_in[29];
    const float* ln_w = (const float*)d_in[30];
    const float* ln_b = (const float*)d_in[31];

    float* out = (float*)d_out;
    char* wsb = (char*)d_ws;

    // ---- workspace layout (bytes); max end 69,730,304 (proven safe) ----
    unsigned short* xr = (unsigned short*)(wsb + 0);
    unsigned short* xk = (unsigned short*)(wsb + 4194304);
    unsigned short* xv = (unsigned short*)(wsb + 8388608);
    unsigned short* xw = (unsigned short*)(wsb + 12582912);
    unsigned short* xa = (unsigned short*)(wsb + 16777216);
    unsigned short* xg = (unsigned short*)(wsb + 20971520);     // ends 25,165,824
    unsigned short* VcT = (unsigned short*)(wsb + 0);           // bf16 VcT[n][vi], post-s1 (8 MiB)
    unsigned short* Gt = (unsigned short*)(wsb + 16777216);     // over xa
    unsigned short* Oi = (unsigned short*)(wsb + 20971520);     // over xg
    // planar pk components (dense 4 MiB each; all dead after prep)
    unsigned short* b_wl = (unsigned short*)(wsb + 25165824);
    unsigned short* b_k  = (unsigned short*)(wsb + 29360128);
    unsigned short* b_a  = (unsigned short*)(wsb + 33554432);
    unsigned short* b_vg = (unsigned short*)(wsb + 37748736);   // ends 41,943,040
    unsigned short* wtD  = (unsigned short*)(wsb + 25165824);   // 2 MiB over dead b_wl
    unsigned short* y_bf = (unsigned short*)(wsb + 27262976);   // 4 MiB over dead planar
    unsigned short* b_r = (unsigned short*)(wsb + 41943040);
    unsigned short* b_v = (unsigned short*)(wsb + 46137344);
    unsigned short* b_o = (unsigned short*)(wsb + 50331648);
    unsigned short* b_g = (unsigned short*)(wsb + 54525952);
    unsigned short* h_cat = (unsigned short*)(wsb + 58720256);
    unsigned short* wt_a1 = (unsigned short*)(wsb + 60293120);
    unsigned short* wt_v1 = (unsigned short*)(wsb + 60424192);
    unsigned short* wt_g1 = (unsigned short*)(wsb + 60489728);
    unsigned short* wt_a2 = (unsigned short*)(wsb + 60817408);
    unsigned short* wt_v2 = (unsigned short*)(wsb + 60948480);
    unsigned short* wt_g2 = (unsigned short*)(wsb + 61014016);
    unsigned short* wt_w1 = (unsigned short*)(wsb + 61341696);
    unsigned short* wt_w2 = (unsigned short*)(wsb + 61472768);
    unsigned short* wtA = (unsigned short*)(wsb + 61603840);
    unsigned short* wtB = (unsigned short*)(wsb + 63700992);
    unsigned short* wtC = (unsigned short*)(wsb + 65798144);    // ends 67,895,296
    unsigned short* LRt = (unsigned short*)(wsb + 60030976);    // 8 MiB over dead wts
    float* Wl = (float*)(wsb + 68419584);
    float* TB = (float*)(wsb + 68681728);

    const dim3 blk(256);

    // 1) stage0: premix + all weight transposes (concurrent, one launch)
    stage0_kernel<<<dim3(4736), blk, 0, stream>>>(
        x, mr, mk, mv, mw, ma, mg, xr, xk, xv, xw, xa, xg,
        W_k, W_v, W_r, w1, a1, v1, g1, a2, v2, g2, w2,
        wtA, wtB, wtC, wt_w1, wt_a1, wt_v1, wt_g1, wt_a2, wt_v2, wt_g2, wt_w2);

    // 2) stage-1 FUSED: r,k,v (128^2 pipelined) + a1,v1,g1,w1 (64^2 pipelined)
    gemm_s1_kernel<<<dim3(576), blk, 0, stream>>>(
        xr, xk, xv, xw, xa, xg, wtA, wtB, wtC,
        wt_a1, wt_v1, wt_g1, wt_w1, b_r, b_k, b_v, h_cat);

    // 3) stage-2: a2, v2, g2, w2 (dense planar outputs)
    gemm_s2_kernel<<<dim3(64, 32), blk, 0, stream>>>(
        h_cat, wt_a2, wt_v2, wt_g2, wt_w2, b_a, b_vg, b_g, b_wl);

    // 4) chunk prep (grid 1024, single chunk/block, fixed LDS overlays)
    chunk_prep_kernel<<<dim3(1024), blk, 0, stream>>>(
        b_wl, b_k, b_a, b_vg, b_r, b_v, v_first, w0, a0, v0, k_k, k_a, r_k,
        TB, Gt, LRt, VcT, Wl, Oi);

    // 5) sequential chunk scan + W_o transpose (fills idle CUs; b_wl dead)
    seq_wtrans_kernel<<<dim3(1152), blk, 0, stream>>>(
        Gt, LRt, VcT, Wl, Oi, b_o, W_o, wtD);

    // 6) groupnorm + bonus + gate
    post_kernel<<<dim3(8192), blk, 0, stream>>>(
        b_o, b_v, b_g, TB, ln_w, ln_b, y_bf);

    // 7) output projection + residual (128x128 pipelined)
    gemm_final128_kernel<<<dim3(8, 16), blk, 0, stream>>>(y_bf, wtD, residual, out);
}